// Round 1
// baseline (1582.048 us; speedup 1.0000x reference)
//
#include <hip/hip_runtime.h>

#define T_    1024
#define B_    2
#define D_    1024
#define E_    12
#define TOPK  4
#define ED_   256
#define HD_   64
#define H_    4
#define N_    (T_*B_)      // 2048 tokens
#define NROW  (N_*TOPK)    // 8192 (n,k) rows
#define S_    8            // attention j-splits
#define NR_   (32*T_)      // 32768 attention rows (bkh,i)
#define RB_MAX 524         // max 16-row expert chunks: 8192/16 + 12

__device__ __forceinline__ float sc_() { return 0.35355339059327373f; } // 64^-0.25

// ---------------- gating: logits -> softmax -> top4 + expert counts ----------
__global__ void gate_kernel(const float* __restrict__ x, const float* __restrict__ wg,
                            float* __restrict__ gates, int* __restrict__ idx,
                            int* __restrict__ counts) {
    int n = blockIdx.x, t = threadIdx.x;   // block = 64 (one wave) per token
    float part[E_];
#pragma unroll
    for (int e = 0; e < E_; ++e) part[e] = 0.f;
    for (int m = 0; m < D_ / 64; ++m) {
        float xv = x[n * D_ + m * 64 + t];
        const float* wr = wg + (m * 64 + t) * E_;
#pragma unroll
        for (int e = 0; e < E_; ++e) part[e] += xv * wr[e];
    }
#pragma unroll
    for (int e = 0; e < E_; ++e) {
        float v = part[e];
        for (int o = 32; o > 0; o >>= 1) v += __shfl_down(v, o);
        part[e] = v;
    }
    if (t == 0) {
        float mx = part[0];
        for (int e = 1; e < E_; ++e) mx = fmaxf(mx, part[e]);
        float s = 0.f, pr[E_];
        for (int e = 0; e < E_; ++e) { pr[e] = expf(part[e] - mx); s += pr[e]; }
        float inv = 1.f / s;
        for (int e = 0; e < E_; ++e) pr[e] *= inv;
        for (int k = 0; k < TOPK; ++k) {
            int be = 0; float bv = -1.f;
            for (int e = 0; e < E_; ++e) if (pr[e] > bv) { bv = pr[e]; be = e; }
            gates[n * TOPK + k] = bv;
            idx[n * TOPK + k] = be;
            pr[be] = -1.f;
            atomicAdd(&counts[be], 1);
        }
    }
}

// ---------------- scan: offsets + 16-row expert chunk map --------------------
__global__ void scan_kernel(const int* __restrict__ counts, int* __restrict__ offs,
                            int* __restrict__ rbe, int* __restrict__ rbs, int* __restrict__ rbc) {
    if (threadIdx.x == 0 && blockIdx.x == 0) {
        int o = 0;
        for (int e = 0; e < E_; ++e) { offs[e] = o; o += counts[e]; }
        offs[E_] = o;
        int nb = 0;
        for (int e = 0; e < E_; ++e) {
            int c = counts[e];
            for (int s = 0; s < c; s += 16) {
                rbe[nb] = e; rbs[nb] = offs[e] + s;
                rbc[nb] = (c - s < 16) ? (c - s) : 16; ++nb;
            }
        }
        for (; nb < RB_MAX; ++nb) { rbe[nb] = 0; rbs[nb] = 0; rbc[nb] = 0; }
    }
}

// ---------------- scatter rows into expert-grouped perm ----------------------
__global__ void scatter_kernel(const int* __restrict__ idx, const int* __restrict__ offs,
                               int* __restrict__ cur, int* __restrict__ perm) {
    int r = blockIdx.x * 256 + threadIdx.x;   // 8192 rows
    int e = idx[r];
    int p = atomicAdd(&cur[e], 1);
    perm[offs[e] + p] = r;
}

// ---------------- k/v projection: kp = key@wk*sc, vp = value@wv --------------
// block = 128 thr (2 waves), 8 token rows, 2 output cols/thread
__global__ void kv_kernel(const float* __restrict__ key, const float* __restrict__ value,
                          const float* __restrict__ wk, const float* __restrict__ wv,
                          float* __restrict__ kp, float* __restrict__ vp) {
    int which = blockIdx.y;
    const float* x = which ? value : key;
    const float* w = which ? wv : wk;
    float* outp = which ? vp : kp;
    float scale = which ? 1.f : sc_();
    int r0 = blockIdx.x * 8;
    int tid = threadIdx.x;
    __shared__ __align__(16) float xs[8][128];
    float acc0[8], acc1[8];
#pragma unroll
    for (int r = 0; r < 8; ++r) { acc0[r] = 0.f; acc1[r] = 0.f; }
    const float* wc = w + tid;
    for (int dt = 0; dt < 8; ++dt) {
        __syncthreads();
#pragma unroll
        for (int q = 0; q < 8; ++q) {
            int el = tid + q * 128, r = el >> 7, dd = el & 127;
            xs[r][dd] = x[(r0 + r) * D_ + dt * 128 + dd];
        }
        __syncthreads();
        for (int dd4 = 0; dd4 < 32; ++dd4) {
            int db = dt * 128 + dd4 * 4;
            float wa0 = wc[(db + 0) * ED_], wa1 = wc[(db + 1) * ED_];
            float wa2 = wc[(db + 2) * ED_], wa3 = wc[(db + 3) * ED_];
            float wb0 = wc[(db + 0) * ED_ + 128], wb1 = wc[(db + 1) * ED_ + 128];
            float wb2 = wc[(db + 2) * ED_ + 128], wb3 = wc[(db + 3) * ED_ + 128];
#pragma unroll
            for (int r = 0; r < 8; ++r) {
                float4 xv = *(const float4*)&xs[r][dd4 * 4];
                acc0[r] += xv.x * wa0 + xv.y * wa1 + xv.z * wa2 + xv.w * wa3;
                acc1[r] += xv.x * wb0 + xv.y * wb1 + xv.z * wb2 + xv.w * wb3;
            }
        }
    }
#pragma unroll
    for (int r = 0; r < 8; ++r) {
        int n = r0 + r;
        int base = (((n & 1) << 10) + (n >> 1)) * ED_;
        outp[base + tid] = acc0[r] * scale;
        outp[base + tid + 128] = acc1[r] * scale;
    }
}

// ---------------- q projection (expert-gathered): qp[row] = x[n]@w_map[e]*sc -
__global__ void qproj_kernel(const float* __restrict__ x, const float* __restrict__ wmap,
                             const int* __restrict__ perm,
                             const int* __restrict__ rbe, const int* __restrict__ rbs,
                             const int* __restrict__ rbc, float* __restrict__ qp) {
    int blk = blockIdx.x;
    int nr = rbc[blk];
    if (nr == 0) return;
    int e = rbe[blk], rs = rbs[blk];
    int tid = threadIdx.x;   // 128
    __shared__ __align__(16) float xs[16][128];
    __shared__ int rows[16];
    if (tid < 16) rows[tid] = (tid < nr) ? perm[rs + tid] : -1;
    float acc0[16], acc1[16];
#pragma unroll
    for (int r = 0; r < 16; ++r) { acc0[r] = 0.f; acc1[r] = 0.f; }
    const float* w0 = wmap + (size_t)e * (D_ * ED_) + tid;
    for (int dt = 0; dt < 8; ++dt) {
        __syncthreads();
#pragma unroll
        for (int q = 0; q < 16; ++q) {
            int el = tid + q * 128, r = el >> 7, dd = el & 127;
            int pr = rows[r];
            xs[r][dd] = (pr >= 0) ? x[(pr >> 2) * D_ + dt * 128 + dd] : 0.f;
        }
        __syncthreads();
        for (int dd4 = 0; dd4 < 32; ++dd4) {
            int db = dt * 128 + dd4 * 4;
            float wa0 = w0[(db + 0) * ED_], wa1 = w0[(db + 1) * ED_];
            float wa2 = w0[(db + 2) * ED_], wa3 = w0[(db + 3) * ED_];
            float wb0 = w0[(db + 0) * ED_ + 128], wb1 = w0[(db + 1) * ED_ + 128];
            float wb2 = w0[(db + 2) * ED_ + 128], wb3 = w0[(db + 3) * ED_ + 128];
#pragma unroll
            for (int r = 0; r < 16; ++r) {
                float4 xv = *(const float4*)&xs[r][dd4 * 4];
                acc0[r] += xv.x * wa0 + xv.y * wa1 + xv.z * wa2 + xv.w * wa3;
                acc1[r] += xv.x * wb0 + xv.y * wb1 + xv.z * wb2 + xv.w * wb3;
            }
        }
    }
    for (int r = 0; r < 16; ++r) {
        if (r < nr) {
            int row = rows[r];
            qp[row * ED_ + tid] = acc0[r] * sc_();
            qp[row * ED_ + tid + 128] = acc1[r] * sc_();
        }
    }
}

// ---------------- rel bias table: rel[bkh,i,p] = q_row . rpe[h,:,p] ----------
__global__ void rel_kernel(const float* __restrict__ qp, const float* __restrict__ rpe,
                           float* __restrict__ rel) {
    int Rr = blockIdx.x * 2 + (threadIdx.x >> 7);
    int p = threadIdx.x & 127;
    int i = Rr & 1023, h = (Rr >> 10) & 3, kk = (Rr >> 12) & 3, bb = Rr >> 14;
    int row = ((i * 2 + bb) << 2) | kk;
    int qbase = __builtin_amdgcn_readfirstlane(row * ED_ + h * HD_);
    int hbase = __builtin_amdgcn_readfirstlane(h * HD_);
    float acc = 0.f;
    for (int d = 0; d < HD_; ++d)
        acc += qp[qbase + d] * rpe[(hbase + d) * 129 + p];
    rel[Rr * 128 + p] = acc;
}

// ---------------- attention partials (no-max softmax, j split S_ ways) -------
__global__ void __launch_bounds__(256, 2)
attn_kernel(const float* __restrict__ qp, const float* __restrict__ kp,
            const float* __restrict__ vp, const float* __restrict__ rel,
            float* __restrict__ po, float* __restrict__ pl) {
    int g = blockIdx.x * 256 + threadIdx.x;
    int lane = g & 63;
    int w = g >> 6;              // 0..4095
    int bkh = w >> 7;            // 0..31
    int s = (w >> 4) & 7;
    int ihi = w & 15;
    int i = (ihi << 6) | lane;   // 0..1023
    int h = bkh & 3, kk = (bkh >> 2) & 3, bb = bkh >> 4;
    int row = ((i * 2 + bb) << 2) | kk;

    const float* qr = qp + row * ED_ + h * HD_;
    float4 q[16];
#pragma unroll
    for (int m = 0; m < 16; ++m) q[m] = *(const float4*)(qr + 4 * m);
    float o[64];
#pragma unroll
    for (int d = 0; d < 64; ++d) o[d] = 0.f;
    float l = 0.f;

    int kvoff = __builtin_amdgcn_readfirstlane((bb << 18) + h * HD_);
    const float* relr = rel + (bkh << 10) * 128 + i * 128;
    int j0 = s * (T_ / S_);
    for (int j = j0; j < j0 + T_ / S_; ++j) {
        const float* kj = kp + kvoff + j * ED_;
        float a0 = 0.f, a1 = 0.f, a2 = 0.f, a3 = 0.f;
#pragma unroll
        for (int m = 0; m < 16; ++m) {
            float4 kv = *(const float4*)(kj + 4 * m);
            a0 += q[m].x * kv.x; a1 += q[m].y * kv.y;
            a2 += q[m].z * kv.z; a3 += q[m].w * kv.w;
        }
        int p = j - i; p = p < -63 ? -63 : (p > 63 ? 63 : p); p += 64;
        float logit = (a0 + a1) + (a2 + a3) + relr[p];
        float pr = __expf(logit);
        l += pr;
        const float* vj = vp + kvoff + j * ED_;
#pragma unroll
        for (int m = 0; m < 16; ++m) {
            float4 vv = *(const float4*)(vj + 4 * m);
            o[4 * m + 0] += pr * vv.x; o[4 * m + 1] += pr * vv.y;
            o[4 * m + 2] += pr * vv.z; o[4 * m + 3] += pr * vv.w;
        }
    }
    int R = (bkh << 10) | i;
    float* por = po + (size_t)(s * NR_ + R) * 64;
#pragma unroll
    for (int m = 0; m < 16; ++m)
        *(float4*)(por + 4 * m) = make_float4(o[4 * m], o[4 * m + 1], o[4 * m + 2], o[4 * m + 3]);
    pl[s * NR_ + R] = l;
}

// ---------------- combine partials + gate weight -> az[row, 256] -------------
__global__ void combine_kernel(const float* __restrict__ po, const float* __restrict__ pl,
                               const float* __restrict__ gates, float* __restrict__ az) {
    int t = blockIdx.x * 256 + threadIdx.x;   // NR_*64 threads
    int R = t >> 6, d = t & 63;
    float os = 0.f;
#pragma unroll
    for (int s = 0; s < S_; ++s) os += po[(size_t)(s * NR_ + R) * 64 + d];
    float ls = 0.f;
#pragma unroll
    for (int s = 0; s < S_; ++s) ls += pl[s * NR_ + R];
    int i = R & 1023, h = (R >> 10) & 3, kk = (R >> 12) & 3, bb = R >> 14;
    int row = ((i * 2 + bb) << 2) | kk;
    az[row * ED_ + h * HD_ + d] = gates[row] * os / ls;
}

// ---------------- expert reduce: out[n] += az[row] @ w_reduce[e] -------------
__global__ void reduce_kernel(const float* __restrict__ az, const float* __restrict__ wr,
                              const int* __restrict__ perm,
                              const int* __restrict__ rbe, const int* __restrict__ rbs,
                              const int* __restrict__ rbc, float* __restrict__ out) {
    int blk = blockIdx.x;
    int nr = rbc[blk];
    if (nr == 0) return;
    int e = rbe[blk], rs = rbs[blk];
    int tid = threadIdx.x;   // 256
    __shared__ __align__(16) float as[16][ED_];
#pragma unroll
    for (int q = 0; q < 16; ++q) {
        int el = tid + q * 256, r = el >> 8, c = el & 255;
        as[r][c] = (r < nr) ? az[perm[rs + r] * ED_ + c] : 0.f;
    }
    __syncthreads();
    float4 acc[16];
#pragma unroll
    for (int r = 0; r < 16; ++r) acc[r] = make_float4(0.f, 0.f, 0.f, 0.f);
    int d0 = tid * 4;
    const float* wbase = wr + (size_t)e * (ED_ * D_) + d0;
    for (int c4 = 0; c4 < 64; ++c4) {
        float4 w0 = *(const float4*)(wbase + (c4 * 4 + 0) * D_);
        float4 w1 = *(const float4*)(wbase + (c4 * 4 + 1) * D_);
        float4 w2 = *(const float4*)(wbase + (c4 * 4 + 2) * D_);
        float4 w3 = *(const float4*)(wbase + (c4 * 4 + 3) * D_);
#pragma unroll
        for (int r = 0; r < 16; ++r) {
            float4 a4 = *(const float4*)&as[r][c4 * 4];
            acc[r].x += a4.x * w0.x + a4.y * w1.x + a4.z * w2.x + a4.w * w3.x;
            acc[r].y += a4.x * w0.y + a4.y * w1.y + a4.z * w2.y + a4.w * w3.y;
            acc[r].z += a4.x * w0.z + a4.y * w1.z + a4.z * w2.z + a4.w * w3.z;
            acc[r].w += a4.x * w0.w + a4.y * w1.w + a4.z * w2.w + a4.w * w3.w;
        }
    }
    for (int r = 0; r < nr; ++r) {
        int n = perm[rs + r] >> 2;
        float* op = out + (size_t)n * D_ + d0;
        atomicAdd(op + 0, acc[r].x);
        atomicAdd(op + 1, acc[r].y);
        atomicAdd(op + 2, acc[r].z);
        atomicAdd(op + 3, acc[r].w);
    }
}

// ---------------- launcher ---------------------------------------------------
extern "C" void kernel_launch(void* const* d_in, const int* in_sizes, int n_in,
                              void* d_out, int out_size, void* d_ws, size_t ws_size,
                              hipStream_t stream) {
    const float* query = (const float*)d_in[0];
    const float* key   = (const float*)d_in[1];
    const float* value = (const float*)d_in[2];
    const float* wg    = (const float*)d_in[3];
    const float* wmap  = (const float*)d_in[4];
    const float* wred  = (const float*)d_in[5];
    const float* wk    = (const float*)d_in[6];
    const float* wv    = (const float*)d_in[7];
    const float* rpe   = (const float*)d_in[8];
    float* out = (float*)d_out;

    char* ws = (char*)d_ws;
    float* gates = (float*)(ws + 0);                       // 32 KB
    int*   idx   = (int*)(ws + (32 << 10));                // 32 KB
    char*  misc  = ws + (64 << 10);
    int*   counts = (int*)(misc + 0);                      // 48 B   [zeroed]
    int*   cur    = (int*)(misc + 64);                     // 48 B   [zeroed]
    int*   offs   = (int*)(misc + 128);                    // 52 B
    int*   rbe    = (int*)(misc + 256);                    // 2096 B
    int*   rbs    = (int*)(misc + 2560);
    int*   rbc    = (int*)(misc + 4864);
    int*   perm  = (int*)(ws + (96 << 10));                // 32 KB
    float* qp    = (float*)(ws + (128 << 10));             // 8 MB
    float* kp    = (float*)(ws + (128 << 10) + (8u << 20));   // 2 MB
    float* vp    = (float*)(ws + (128 << 10) + (10u << 20));  // 2 MB
    float* rel   = (float*)(ws + (128 << 10) + (12u << 20));  // 16 MB
    float* po    = (float*)(ws + (128 << 10) + (28u << 20));  // 64 MB
    float* pl    = (float*)(ws + (128 << 10) + (92u << 20));  // 1 MB
    float* az    = (float*)(ws + (128 << 10) + (93u << 20));  // 8 MB

    hipMemsetAsync(misc, 0, 128, stream);
    hipMemsetAsync(out, 0, (size_t)out_size * sizeof(float), stream);

    gate_kernel<<<N_, 64, 0, stream>>>(query, wg, gates, idx, counts);
    scan_kernel<<<1, 64, 0, stream>>>(counts, offs, rbe, rbs, rbc);
    scatter_kernel<<<NROW / 256, 256, 0, stream>>>(idx, offs, cur, perm);
    kv_kernel<<<dim3(N_ / 8, 2), 128, 0, stream>>>(key, value, wk, wv, kp, vp);
    qproj_kernel<<<RB_MAX, 128, 0, stream>>>(query, wmap, perm, rbe, rbs, rbc, qp);
    rel_kernel<<<NR_ / 2, 256, 0, stream>>>(qp, rpe, rel);
    attn_kernel<<<(NR_ * S_) / 256, 256, 0, stream>>>(qp, kp, vp, rel, po, pl);
    combine_kernel<<<(NR_ * 64) / 256, 256, 0, stream>>>(po, pl, gates, az);
    reduce_kernel<<<RB_MAX, 256, 0, stream>>>(az, wred, perm, rbe, rbs, rbc, out);
}

// Round 2
// 734.036 us; speedup vs baseline: 2.1553x; 2.1553x over previous
//
#include <hip/hip_runtime.h>

#define T_    1024
#define B_    2
#define D_    1024
#define E_    12
#define TOPK  4
#define ED_   256
#define HD_   64
#define H_    4
#define N_    (T_*B_)      // 2048 tokens
#define NROW  (N_*TOPK)    // 8192 (n,k) rows
#define RB_MAX 524         // max 16-row expert chunks: 8192/16 + 12

typedef __bf16 bf16x8 __attribute__((ext_vector_type(8)));
typedef float  f32x4  __attribute__((ext_vector_type(4)));

__device__ __forceinline__ float sc_() { return 0.35355339059327373f; } // 64^-0.25

__device__ __forceinline__ void async16(const void* g, void* l) {
    __builtin_amdgcn_global_load_lds((const __attribute__((address_space(1))) void*)g,
                                     (__attribute__((address_space(3))) void*)l, 16, 0, 0);
}

// ---------------- gating: logits -> softmax -> top4 + expert counts ----------
__global__ void gate_kernel(const float* __restrict__ x, const float* __restrict__ wg,
                            float* __restrict__ gates, int* __restrict__ idx,
                            int* __restrict__ counts) {
    int n = blockIdx.x, t = threadIdx.x;   // block = 64 (one wave) per token
    float part[E_];
#pragma unroll
    for (int e = 0; e < E_; ++e) part[e] = 0.f;
    for (int m = 0; m < D_ / 64; ++m) {
        float xv = x[n * D_ + m * 64 + t];
        const float* wr = wg + (m * 64 + t) * E_;
#pragma unroll
        for (int e = 0; e < E_; ++e) part[e] += xv * wr[e];
    }
#pragma unroll
    for (int e = 0; e < E_; ++e) {
        float v = part[e];
        for (int o = 32; o > 0; o >>= 1) v += __shfl_down(v, o);
        part[e] = v;
    }
    if (t == 0) {
        float mx = part[0];
        for (int e = 1; e < E_; ++e) mx = fmaxf(mx, part[e]);
        float s = 0.f, pr[E_];
        for (int e = 0; e < E_; ++e) { pr[e] = expf(part[e] - mx); s += pr[e]; }
        float inv = 1.f / s;
        for (int e = 0; e < E_; ++e) pr[e] *= inv;
        for (int k = 0; k < TOPK; ++k) {
            int be = 0; float bv = -1.f;
            for (int e = 0; e < E_; ++e) if (pr[e] > bv) { bv = pr[e]; be = e; }
            gates[n * TOPK + k] = bv;
            idx[n * TOPK + k] = be;
            pr[be] = -1.f;
            atomicAdd(&counts[be], 1);
        }
    }
}

// ---------------- scan: offsets + 16-row expert chunk map --------------------
__global__ void scan_kernel(const int* __restrict__ counts, int* __restrict__ offs,
                            int* __restrict__ rbe, int* __restrict__ rbs, int* __restrict__ rbc) {
    if (threadIdx.x == 0 && blockIdx.x == 0) {
        int o = 0;
        for (int e = 0; e < E_; ++e) { offs[e] = o; o += counts[e]; }
        offs[E_] = o;
        int nb = 0;
        for (int e = 0; e < E_; ++e) {
            int c = counts[e];
            for (int s = 0; s < c; s += 16) {
                rbe[nb] = e; rbs[nb] = offs[e] + s;
                rbc[nb] = (c - s < 16) ? (c - s) : 16; ++nb;
            }
        }
        for (; nb < RB_MAX; ++nb) { rbe[nb] = 0; rbs[nb] = 0; rbc[nb] = 0; }
    }
}

// ---------------- scatter rows into expert-grouped perm ----------------------
__global__ void scatter_kernel(const int* __restrict__ idx, const int* __restrict__ offs,
                               int* __restrict__ cur, int* __restrict__ perm) {
    int r = blockIdx.x * 256 + threadIdx.x;   // 8192 rows
    int e = idx[r];
    int p = atomicAdd(&cur[e], 1);
    perm[offs[e] + p] = r;
}

// ---------------- k/v projection -> bf16 K (natural) and bf16 V^T ------------
// block = 128 thr, 8 token rows, cols (2*tid, 2*tid+1)
__global__ void kv_kernel(const float* __restrict__ key, const float* __restrict__ value,
                          const float* __restrict__ wk, const float* __restrict__ wv,
                          ushort* __restrict__ kpb, ushort* __restrict__ vpT) {
    int which = blockIdx.y;
    const float* x = which ? value : key;
    const float* wgt = which ? wv : wk;
    float scale = which ? 1.f : sc_();
    int r0 = blockIdx.x * 8;
    int tid = threadIdx.x;
    __shared__ __align__(16) float xs[8][128];
    float2 acc[8];
#pragma unroll
    for (int r = 0; r < 8; ++r) acc[r] = make_float2(0.f, 0.f);
    const float* wc = wgt + 2 * tid;
    for (int dt = 0; dt < 8; ++dt) {
        __syncthreads();
#pragma unroll
        for (int q = 0; q < 8; ++q) {
            int el = tid + q * 128, r = el >> 7, dd = el & 127;
            xs[r][dd] = x[(r0 + r) * D_ + dt * 128 + dd];
        }
        __syncthreads();
        for (int dd4 = 0; dd4 < 32; ++dd4) {
            int db = dt * 128 + dd4 * 4;
            float2 w0 = *(const float2*)(wc + (db + 0) * ED_);
            float2 w1 = *(const float2*)(wc + (db + 1) * ED_);
            float2 w2 = *(const float2*)(wc + (db + 2) * ED_);
            float2 w3 = *(const float2*)(wc + (db + 3) * ED_);
#pragma unroll
            for (int r = 0; r < 8; ++r) {
                float4 xv = *(const float4*)&xs[r][dd4 * 4];
                acc[r].x += xv.x * w0.x + xv.y * w1.x + xv.z * w2.x + xv.w * w3.x;
                acc[r].y += xv.x * w0.y + xv.y * w1.y + xv.z * w2.y + xv.w * w3.y;
            }
        }
    }
    int ed0 = 2 * tid, h0 = ed0 >> 6, d0 = ed0 & 63;
    if (which == 0) {
#pragma unroll
        for (int r = 0; r < 8; ++r) {
            int n = r0 + r, b = n & 1, t = n >> 1;
            union { __bf16 h2[2]; uint u; } pk;
            pk.h2[0] = (__bf16)(acc[r].x * scale);
            pk.h2[1] = (__bf16)(acc[r].y * scale);
            *(uint*)&kpb[((b << 10) + t) * ED_ + ed0] = pk.u;
        }
    } else {
        int t0 = r0 >> 1;
#pragma unroll
        for (int b = 0; b < 2; ++b) {
            union { __bf16 h4[4]; uint2 u; } p0, p1;
#pragma unroll
            for (int q = 0; q < 4; ++q) {
                float2 a = acc[b + 2 * q];
                p0.h4[q] = (__bf16)a.x;
                p1.h4[q] = (__bf16)a.y;
            }
            *(uint2*)&vpT[((size_t)((b * 4 + h0) * 64 + d0)) * 1024 + t0] = p0.u;
            *(uint2*)&vpT[((size_t)((b * 4 + h0) * 64 + d0 + 1)) * 1024 + t0] = p1.u;
        }
    }
}

// ---------------- q projection (expert-gathered), f32 + bf16 outputs ---------
// grid = RB_MAX*2 (chunk, col-half), block = 128 thr, 1 col/thread
__global__ void qproj_kernel(const float* __restrict__ x, const float* __restrict__ wmap,
                             const int* __restrict__ perm,
                             const int* __restrict__ rbe, const int* __restrict__ rbs,
                             const int* __restrict__ rbc, float* __restrict__ qp,
                             ushort* __restrict__ qpb) {
    int blk = blockIdx.x >> 1, half = blockIdx.x & 1;
    int nr = rbc[blk];
    if (nr == 0) return;
    int e = rbe[blk], rs = rbs[blk];
    int tid = threadIdx.x;   // 128
    int col = half * 128 + tid;
    __shared__ __align__(16) float xs[16][128];
    __shared__ int rows[16];
    if (tid < 16) rows[tid] = (tid < nr) ? perm[rs + tid] : -1;
    float acc[16];
#pragma unroll
    for (int r = 0; r < 16; ++r) acc[r] = 0.f;
    const float* w0 = wmap + (size_t)e * (D_ * ED_) + col;
    for (int dt = 0; dt < 8; ++dt) {
        __syncthreads();
#pragma unroll
        for (int q = 0; q < 16; ++q) {
            int el = tid + q * 128, r = el >> 7, dd = el & 127;
            int pr = rows[r];
            xs[r][dd] = (pr >= 0) ? x[(pr >> 2) * D_ + dt * 128 + dd] : 0.f;
        }
        __syncthreads();
        for (int dd4 = 0; dd4 < 32; ++dd4) {
            int db = dt * 128 + dd4 * 4;
            float wa0 = w0[(db + 0) * ED_], wa1 = w0[(db + 1) * ED_];
            float wa2 = w0[(db + 2) * ED_], wa3 = w0[(db + 3) * ED_];
#pragma unroll
            for (int r = 0; r < 16; ++r) {
                float4 xv = *(const float4*)&xs[r][dd4 * 4];
                acc[r] += xv.x * wa0 + xv.y * wa1 + xv.z * wa2 + xv.w * wa3;
            }
        }
    }
    for (int r = 0; r < 16; ++r) {
        if (r < nr) {
            int row = rows[r];
            float v = acc[r] * sc_();
            qp[row * ED_ + col] = v;
            union { __bf16 h; ushort u; } cv; cv.h = (__bf16)v;
            qpb[row * ED_ + col] = cv.u;
        }
    }
}

// ---------------- rel bias table: rel[bkh,i,p] = q_row . rpe[h,:,p] ----------
__global__ void rel_kernel(const float* __restrict__ qp, const float* __restrict__ rpe,
                           float* __restrict__ rel) {
    int Rr = blockIdx.x * 2 + (threadIdx.x >> 7);
    int p = threadIdx.x & 127;
    int i = Rr & 1023, h = (Rr >> 10) & 3, kk = (Rr >> 12) & 3, bb = Rr >> 14;
    int row = ((i * 2 + bb) << 2) | kk;
    int qbase = __builtin_amdgcn_readfirstlane(row * ED_ + h * HD_);
    int hbase = __builtin_amdgcn_readfirstlane(h * HD_);
    float acc = 0.f;
    for (int d = 0; d < HD_; ++d)
        acc += qp[qbase + d] * rpe[(hbase + d) * 129 + p];
    rel[Rr * 128 + p] = acc;
}

// ---------------- MFMA flash attention (bf16, no-max softmax) ----------------
// block = 256 thr (4 waves), 64 i-rows/block (16/wave), j tiles of 64.
// S^T = K.Q^T (so P round-trips LDS with 8B writes / b128 reads), O^T = V^T.P^T.
__global__ void __launch_bounds__(256)
attn_kernel(const ushort* __restrict__ qpb, const ushort* __restrict__ kpb,
            const ushort* __restrict__ vpT, const float* __restrict__ rel,
            const float* __restrict__ gates, float* __restrict__ az) {
    __shared__ __align__(16) ushort Ks[2][64 * 64];    // [j][d] 8KB x2
    __shared__ __align__(16) ushort Vs[2][64 * 64];    // [d][j] 8KB x2
    __shared__ __align__(16) ushort Ps[4][16 * 64];    // per-wave P [i][j] 2KB x4

    const int tid = threadIdx.x;
    const int w = tid >> 6, L = tid & 63;
    const int bkh = blockIdx.x & 31, it = blockIdx.x >> 5;
    const int h = bkh & 3, kk = (bkh >> 2) & 3, bb = bkh >> 4;
    const int i0w = it * 64 + w * 16;
    const int iL = i0w + (L & 15);
    const int row = ((iL * 2 + bb) << 2) | kk;

    // persistent Q B-frags: B[k=d][n=i], lane: n=L&15, k=(L>>4)*8+jj
    const ushort* qrow = qpb + row * ED_ + h * HD_;
    bf16x8 qf0 = *(const bf16x8*)(qrow + (L >> 4) * 8);
    bf16x8 qf1 = *(const bf16x8*)(qrow + 32 + (L >> 4) * 8);

    const float* relrow = rel + ((size_t)((bkh << 10) + iL)) * 128;
    float rel_lo = relrow[1], rel_hi = relrow[127];
    float gate = gates[row];

    f32x4 O[4];
#pragma unroll
    for (int mf = 0; mf < 4; ++mf) O[mf] = (f32x4){0.f, 0.f, 0.f, 0.f};
    float l_acc = 0.f;

    const ushort* ksrc = kpb + (size_t)(bb << 10) * ED_ + h * HD_;
    const ushort* vsrc = vpT + (size_t)((bb * 4 + h) * 64) * 1024;

    auto stage = [&](int t, int bf) {
        int j0 = t * 64;
        // K: 64 rows x 128B; wave stages rows w*16..+16, 2 calls x 8 rows
#pragma unroll
        for (int q = 0; q < 2; ++q) {
            int r = L >> 3;                       // 0..7
            int c = (L & 7) ^ r;                  // chunk XOR-swizzle
            const ushort* src = ksrc + (size_t)(j0 + w * 16 + q * 8 + r) * ED_ + c * 8;
            async16(src, &Ks[bf][(w * 16 + q * 8) * 64]);
        }
        // V^T: 64 d-rows x 128B; wave stages rows w*16..+16, 2 calls x 8 rows
#pragma unroll
        for (int q = 0; q < 2; ++q) {
            int r = L >> 3;
            int d = w * 16 + q * 8 + r;
            int c = (L & 7) ^ (d & 7);
            const ushort* src = vsrc + (size_t)d * 1024 + j0 + c * 8;
            async16(src, &Vs[bf][(w * 16 + q * 8) * 64]);
        }
    };

    auto compute = [&](int bf, int j0) {
        const ushort* KB = Ks[bf];
        const ushort* VB = Vs[bf];
        ushort* PW = Ps[w];
        // ---- S^T = K.Q^T, fixup, exp, -> P LDS ----
#pragma unroll
        for (int jf = 0; jf < 4; ++jf) {
            int jrow = jf * 16 + (L & 15);
            bf16x8 a0 = *(const bf16x8*)(KB + jrow * 64 + (((L >> 4)) ^ (L & 7)) * 8);
            bf16x8 a1 = *(const bf16x8*)(KB + jrow * 64 + ((4 + (L >> 4)) ^ (L & 7)) * 8);
            f32x4 s = (f32x4){0.f, 0.f, 0.f, 0.f};
            s = __builtin_amdgcn_mfma_f32_16x16x32_bf16(a0, qf0, s, 0, 0, 0);
            s = __builtin_amdgcn_mfma_f32_16x16x32_bf16(a1, qf1, s, 0, 0, 0);
            int jlo = j0 + jf * 16;
            int jbase = jlo + (L >> 4) * 4;
            float pv[4];
            if (jlo >= i0w + 78) {                 // all dj >= 63
#pragma unroll
                for (int r = 0; r < 4; ++r) pv[r] = __expf(s[r] + rel_hi);
            } else if (jlo <= i0w - 78) {          // all dj <= -63
#pragma unroll
                for (int r = 0; r < 4; ++r) pv[r] = __expf(s[r] + rel_lo);
            } else {
#pragma unroll
                for (int r = 0; r < 4; ++r) {
                    int dj = jbase + r - iL;
                    dj = dj < -63 ? -63 : (dj > 63 ? 63 : dj);
                    pv[r] = __expf(s[r] + relrow[dj + 64]);
                }
            }
            l_acc += (pv[0] + pv[1]) + (pv[2] + pv[3]);
            union { __bf16 h4[4]; uint2 u; } pk;
#pragma unroll
            for (int r = 0; r < 4; ++r) pk.h4[r] = (__bf16)pv[r];
            int iloc = L & 15;
            int chunk = jf * 2 + ((L >> 4) >> 1);
            int phys = chunk ^ (iloc & 7);
            *(uint2*)(PW + iloc * 64 + phys * 8 + ((L >> 4) & 1) * 4) = pk.u;
        }
        // ---- O^T += V^T.P^T ----
#pragma unroll
        for (int ks = 0; ks < 2; ++ks) {
            int c = ks * 4 + (L >> 4);
            int phys = c ^ (L & 7);
            bf16x8 pf = *(const bf16x8*)(PW + (L & 15) * 64 + phys * 8);
#pragma unroll
            for (int mf = 0; mf < 4; ++mf) {
                bf16x8 vf = *(const bf16x8*)(VB + (mf * 16 + (L & 15)) * 64 + phys * 8);
                O[mf] = __builtin_amdgcn_mfma_f32_16x16x32_bf16(vf, pf, O[mf], 0, 0, 0);
            }
        }
    };

    stage(0, 0);
    for (int t = 0; t < 16; ++t) {
        __syncthreads();                 // drains vmcnt for tile t's global_load_lds
        if (t < 15) stage(t + 1, (t + 1) & 1);
        compute(t & 1, t * 64);
    }

    // epilogue: reduce l over the 4 lane-groups holding the same i
    l_acc += __shfl_xor(l_acc, 16);
    l_acc += __shfl_xor(l_acc, 32);
    float inv = gate / l_acc;
    float* azrow = az + (size_t)row * ED_ + h * HD_;
#pragma unroll
    for (int mf = 0; mf < 4; ++mf) {
        f32x4 o = O[mf] * inv;
        *(f32x4*)(azrow + mf * 16 + (L >> 4) * 4) = o;
    }
}

// ---------------- expert reduce: out[n] += az[row] @ w_reduce[e] -------------
// grid = RB_MAX*2 (chunk, d-half), block = 256, 2 cols/thread
__global__ void reduce_kernel(const float* __restrict__ az, const float* __restrict__ wr,
                              const int* __restrict__ perm,
                              const int* __restrict__ rbe, const int* __restrict__ rbs,
                              const int* __restrict__ rbc, float* __restrict__ out) {
    int blk = blockIdx.x >> 1, half = blockIdx.x & 1;
    int nr = rbc[blk];
    if (nr == 0) return;
    int e = rbe[blk], rs = rbs[blk];
    int tid = threadIdx.x;   // 256
    __shared__ __align__(16) float as[16][ED_];
#pragma unroll
    for (int q = 0; q < 16; ++q) {
        int el = tid + q * 256, r = el >> 8, c = el & 255;
        as[r][c] = (r < nr) ? az[(size_t)perm[rs + r] * ED_ + c] : 0.f;
    }
    __syncthreads();
    float2 acc[16];
#pragma unroll
    for (int r = 0; r < 16; ++r) acc[r] = make_float2(0.f, 0.f);
    int d0 = half * 512 + 2 * tid;
    const float* wbase = wr + (size_t)e * (ED_ * D_) + d0;
    for (int c4 = 0; c4 < 64; ++c4) {
        float2 w0 = *(const float2*)(wbase + (size_t)(c4 * 4 + 0) * D_);
        float2 w1 = *(const float2*)(wbase + (size_t)(c4 * 4 + 1) * D_);
        float2 w2 = *(const float2*)(wbase + (size_t)(c4 * 4 + 2) * D_);
        float2 w3 = *(const float2*)(wbase + (size_t)(c4 * 4 + 3) * D_);
#pragma unroll
        for (int r = 0; r < 16; ++r) {
            float4 a4 = *(const float4*)&as[r][c4 * 4];
            acc[r].x += a4.x * w0.x + a4.y * w1.x + a4.z * w2.x + a4.w * w3.x;
            acc[r].y += a4.x * w0.y + a4.y * w1.y + a4.z * w2.y + a4.w * w3.y;
        }
    }
    for (int r = 0; r < nr; ++r) {
        int n = perm[rs + r] >> 2;
        float* op = out + (size_t)n * D_ + d0;
        atomicAdd(op + 0, acc[r].x);
        atomicAdd(op + 1, acc[r].y);
    }
}

// ---------------- launcher ---------------------------------------------------
extern "C" void kernel_launch(void* const* d_in, const int* in_sizes, int n_in,
                              void* d_out, int out_size, void* d_ws, size_t ws_size,
                              hipStream_t stream) {
    const float* query = (const float*)d_in[0];
    const float* key   = (const float*)d_in[1];
    const float* value = (const float*)d_in[2];
    const float* wg    = (const float*)d_in[3];
    const float* wmap  = (const float*)d_in[4];
    const float* wred  = (const float*)d_in[5];
    const float* wk    = (const float*)d_in[6];
    const float* wv    = (const float*)d_in[7];
    const float* rpe   = (const float*)d_in[8];
    float* out = (float*)d_out;

    char* ws = (char*)d_ws;
    float*  gates = (float*)(ws + 0);                      // 32 KB
    int*    idx   = (int*)(ws + (32 << 10));               // 32 KB
    char*   misc  = ws + (64 << 10);
    int*    counts = (int*)(misc + 0);                     // [zeroed]
    int*    cur    = (int*)(misc + 64);                    // [zeroed]
    int*    offs   = (int*)(misc + 128);
    int*    rbe    = (int*)(misc + 256);
    int*    rbs    = (int*)(misc + 2560);
    int*    rbc    = (int*)(misc + 4864);
    int*    perm  = (int*)(ws + (96 << 10));               // 32 KB
    float*  qp    = (float*)(ws + (128 << 10));            // 8 MB  f32 (rel input)
    ushort* qpb   = (ushort*)(ws + (128 << 10) + (8u  << 20));  // 4 MB bf16
    ushort* kpb   = (ushort*)(ws + (128 << 10) + (12u << 20)); // 1 MB bf16 [b][t][ed]
    ushort* vpT   = (ushort*)(ws + (128 << 10) + (13u << 20)); // 1 MB bf16 [b][h][d][t]
    float*  rel   = (float*)(ws + (128 << 10) + (14u << 20));  // 16 MB
    float*  az    = (float*)(ws + (128 << 10) + (30u << 20));  // 8 MB

    hipMemsetAsync(misc, 0, 128, stream);
    hipMemsetAsync(out, 0, (size_t)out_size * sizeof(float), stream);

    gate_kernel<<<N_, 64, 0, stream>>>(query, wg, gates, idx, counts);
    scan_kernel<<<1, 64, 0, stream>>>(counts, offs, rbe, rbs, rbc);
    scatter_kernel<<<NROW / 256, 256, 0, stream>>>(idx, offs, cur, perm);
    kv_kernel<<<dim3(N_ / 8, 2), 128, 0, stream>>>(key, value, wk, wv, kpb, vpT);
    qproj_kernel<<<RB_MAX * 2, 128, 0, stream>>>(query, wmap, perm, rbe, rbs, rbc, qp, qpb);
    rel_kernel<<<(32 * T_) / 2, 256, 0, stream>>>(qp, rpe, rel);
    attn_kernel<<<512, 256, 0, stream>>>(qpb, kpb, vpT, rel, gates, az);
    reduce_kernel<<<RB_MAX * 2, 256, 0, stream>>>(az, wred, perm, rbe, rbs, rbc, out);
}

// Round 3
// 584.910 us; speedup vs baseline: 2.7048x; 1.2550x over previous
//
#include <hip/hip_runtime.h>

#define T_    1024
#define B_    2
#define D_    1024
#define E_    12
#define TOPK  4
#define ED_   256
#define HD_   64
#define H_    4
#define N_    (T_*B_)      // 2048 tokens
#define NROW  (N_*TOPK)    // 8192 (n,k) rows
#define RB_MAX 524         // max 16-row expert chunks: 8192/16 + 12
#define PB_MAX 268         // max 32-row expert chunks: 8192/32 + 12

typedef __bf16 bf16x8 __attribute__((ext_vector_type(8)));
typedef float  f32x4  __attribute__((ext_vector_type(4)));

__device__ __forceinline__ float sc_() { return 0.35355339059327373f; } // 64^-0.25

__device__ __forceinline__ void async16(const void* g, void* l) {
    __builtin_amdgcn_global_load_lds((const __attribute__((address_space(1))) void*)g,
                                     (__attribute__((address_space(3))) void*)l, 16, 0, 0);
}

// ---------------- gating: logits -> softmax -> top4 + expert counts ----------
__global__ void gate_kernel(const float* __restrict__ x, const float* __restrict__ wg,
                            float* __restrict__ gates, int* __restrict__ idx,
                            int* __restrict__ counts) {
    int n = blockIdx.x, t = threadIdx.x;   // block = 64 (one wave) per token
    float part[E_];
#pragma unroll
    for (int e = 0; e < E_; ++e) part[e] = 0.f;
    for (int m = 0; m < D_ / 64; ++m) {
        float xv = x[n * D_ + m * 64 + t];
        const float* wr = wg + (m * 64 + t) * E_;
#pragma unroll
        for (int e = 0; e < E_; ++e) part[e] += xv * wr[e];
    }
#pragma unroll
    for (int e = 0; e < E_; ++e) {
        float v = part[e];
        for (int o = 32; o > 0; o >>= 1) v += __shfl_down(v, o);
        part[e] = v;
    }
    if (t == 0) {
        float mx = part[0];
        for (int e = 1; e < E_; ++e) mx = fmaxf(mx, part[e]);
        float s = 0.f, pr[E_];
        for (int e = 0; e < E_; ++e) { pr[e] = expf(part[e] - mx); s += pr[e]; }
        float inv = 1.f / s;
        for (int e = 0; e < E_; ++e) pr[e] *= inv;
        for (int k = 0; k < TOPK; ++k) {
            int be = 0; float bv = -1.f;
            for (int e = 0; e < E_; ++e) if (pr[e] > bv) { bv = pr[e]; be = e; }
            gates[n * TOPK + k] = bv;
            idx[n * TOPK + k] = be;
            pr[be] = -1.f;
            atomicAdd(&counts[be], 1);
        }
    }
}

// ---------------- scan: offsets + 16-row and 32-row expert chunk maps --------
__global__ void scan_kernel(const int* __restrict__ counts, int* __restrict__ offs,
                            int* __restrict__ rbe, int* __restrict__ rbs, int* __restrict__ rbc,
                            int* __restrict__ rbe2, int* __restrict__ rbs2, int* __restrict__ rbc2) {
    if (threadIdx.x == 0 && blockIdx.x == 0) {
        int o = 0;
        for (int e = 0; e < E_; ++e) { offs[e] = o; o += counts[e]; }
        offs[E_] = o;
        int nb = 0;
        for (int e = 0; e < E_; ++e) {
            int c = counts[e];
            for (int s = 0; s < c; s += 16) {
                rbe[nb] = e; rbs[nb] = offs[e] + s;
                rbc[nb] = (c - s < 16) ? (c - s) : 16; ++nb;
            }
        }
        for (; nb < RB_MAX; ++nb) { rbe[nb] = 0; rbs[nb] = 0; rbc[nb] = 0; }
        int nb2 = 0;
        for (int e = 0; e < E_; ++e) {
            int c = counts[e];
            for (int s = 0; s < c; s += 32) {
                rbe2[nb2] = e; rbs2[nb2] = offs[e] + s;
                rbc2[nb2] = (c - s < 32) ? (c - s) : 32; ++nb2;
            }
        }
        for (; nb2 < PB_MAX; ++nb2) { rbe2[nb2] = 0; rbs2[nb2] = 0; rbc2[nb2] = 0; }
    }
}

// ---------------- scatter rows into expert-grouped perm ----------------------
__global__ void scatter_kernel(const int* __restrict__ idx, const int* __restrict__ offs,
                               int* __restrict__ cur, int* __restrict__ perm) {
    int r = blockIdx.x * 256 + threadIdx.x;   // 8192 rows
    int e = idx[r];
    int p = atomicAdd(&cur[e], 1);
    perm[offs[e] + p] = r;
}

// ---------------- one-time casts: x -> bf16, w_map -> bf16 transposed --------
__global__ void castx_kernel(const float* __restrict__ x, ushort* __restrict__ xb) {
    int t = blockIdx.x * 256 + threadIdx.x;
    float4 v = *(const float4*)(x + (size_t)t * 4);
    union { __bf16 h[4]; uint2 u; } pk;
    pk.h[0] = (__bf16)v.x; pk.h[1] = (__bf16)v.y;
    pk.h[2] = (__bf16)v.z; pk.h[3] = (__bf16)v.w;
    *(uint2*)(xb + (size_t)t * 4) = pk.u;
}

// grid (12,16,4): e, 64-d tile, 64-ed tile.  wmapT[e][ed][d] = bf16(w_map[e][d][ed])
__global__ void castw_kernel(const float* __restrict__ wmap, ushort* __restrict__ wmapT) {
    int e = blockIdx.x, dt = blockIdx.y, et = blockIdx.z;
    __shared__ float ls[64][65];
    int c = threadIdx.x & 63, rg = threadIdx.x >> 6;
    const float* src = wmap + (size_t)e * (D_ * ED_) + (size_t)(dt * 64) * ED_ + et * 64;
#pragma unroll
    for (int q = 0; q < 16; ++q) {
        int r = q * 4 + rg;
        ls[r][c] = src[(size_t)r * ED_ + c];
    }
    __syncthreads();
    ushort* dst = wmapT + ((size_t)e << 18) + (size_t)(et * 64) * 1024 + dt * 64;
#pragma unroll
    for (int q = 0; q < 16; ++q) {
        int r = q * 4 + rg;
        union { __bf16 h; ushort u; } cv; cv.h = (__bf16)ls[c][r];
        dst[(size_t)r * 1024 + c] = cv.u;
    }
}

// ---------------- k/v projection -> bf16 K (natural) and bf16 V^T ------------
// block = 128 thr, 8 token rows, cols (2*tid, 2*tid+1)
__global__ void kv_kernel(const float* __restrict__ key, const float* __restrict__ value,
                          const float* __restrict__ wk, const float* __restrict__ wv,
                          ushort* __restrict__ kpb, ushort* __restrict__ vpT) {
    int which = blockIdx.y;
    const float* x = which ? value : key;
    const float* wgt = which ? wv : wk;
    float scale = which ? 1.f : sc_();
    int r0 = blockIdx.x * 8;
    int tid = threadIdx.x;
    __shared__ __align__(16) float xs[8][128];
    float2 acc[8];
#pragma unroll
    for (int r = 0; r < 8; ++r) acc[r] = make_float2(0.f, 0.f);
    const float* wc = wgt + 2 * tid;
    for (int dt = 0; dt < 8; ++dt) {
        __syncthreads();
#pragma unroll
        for (int q = 0; q < 8; ++q) {
            int el = tid + q * 128, r = el >> 7, dd = el & 127;
            xs[r][dd] = x[(r0 + r) * D_ + dt * 128 + dd];
        }
        __syncthreads();
        for (int dd4 = 0; dd4 < 32; ++dd4) {
            int db = dt * 128 + dd4 * 4;
            float2 w0 = *(const float2*)(wc + (db + 0) * ED_);
            float2 w1 = *(const float2*)(wc + (db + 1) * ED_);
            float2 w2 = *(const float2*)(wc + (db + 2) * ED_);
            float2 w3 = *(const float2*)(wc + (db + 3) * ED_);
#pragma unroll
            for (int r = 0; r < 8; ++r) {
                float4 xv = *(const float4*)&xs[r][dd4 * 4];
                acc[r].x += xv.x * w0.x + xv.y * w1.x + xv.z * w2.x + xv.w * w3.x;
                acc[r].y += xv.x * w0.y + xv.y * w1.y + xv.z * w2.y + xv.w * w3.y;
            }
        }
    }
    int ed0 = 2 * tid, h0 = ed0 >> 6, d0 = ed0 & 63;
    if (which == 0) {
#pragma unroll
        for (int r = 0; r < 8; ++r) {
            int n = r0 + r, b = n & 1, t = n >> 1;
            union { __bf16 h2[2]; uint u; } pk;
            pk.h2[0] = (__bf16)(acc[r].x * scale);
            pk.h2[1] = (__bf16)(acc[r].y * scale);
            *(uint*)&kpb[((b << 10) + t) * ED_ + ed0] = pk.u;
        }
    } else {
        int t0 = r0 >> 1;
#pragma unroll
        for (int b = 0; b < 2; ++b) {
            union { __bf16 h4[4]; uint2 u; } p0, p1;
#pragma unroll
            for (int q = 0; q < 4; ++q) {
                float2 a = acc[b + 2 * q];
                p0.h4[q] = (__bf16)a.x;
                p1.h4[q] = (__bf16)a.y;
            }
            *(uint2*)&vpT[((size_t)((b * 4 + h0) * 64 + d0)) * 1024 + t0] = p0.u;
            *(uint2*)&vpT[((size_t)((b * 4 + h0) * 64 + d0 + 1)) * 1024 + t0] = p1.u;
        }
    }
}

// ---------------- q projection as bf16 MFMA GEMM per 32-row expert chunk -----
// block = 256 thr (4 waves), M=32, N=256 (wave w: cols w*64..+63), K=1024 (BK=64, dbuf)
__global__ void __launch_bounds__(256)
qproj_mfma(const ushort* __restrict__ xb, const ushort* __restrict__ wmapT,
           const int* __restrict__ perm,
           const int* __restrict__ rbe2, const int* __restrict__ rbs2,
           const int* __restrict__ rbc2,
           float* __restrict__ qp, ushort* __restrict__ qpb) {
    int blk = blockIdx.x;
    int nr = rbc2[blk];
    if (nr == 0) return;
    int e = rbe2[blk], rs = rbs2[blk];
    int tid = threadIdx.x, w = tid >> 6, L = tid & 63;
    __shared__ __align__(16) ushort As[2][32 * 64];       // 4 KB x2, [m][k] swizzled
    __shared__ __align__(16) ushort Bs[2][4 * 64 * 64];   // 32 KB x2, [n][k] swizzled
    __shared__ int rows2[32];
    if (tid < 32) rows2[tid] = (tid < nr) ? perm[rs + tid] : -1;
    __syncthreads();

    int swz = ((L & 7) ^ ((L >> 3) & 7)) * 8;             // ushort offset of 16B chunk
    int ar = rows2[w * 8 + (L >> 3)];                     // wave w stages A rows w*8..+7
    const ushort* asrc = xb + (size_t)((ar < 0 ? 0 : ar) >> 2) * 1024 + swz;
    const ushort* bsrc = wmapT + ((size_t)e << 18) + (size_t)(w * 64 + (L >> 3)) * 1024 + swz;

    f32x4 acc[2][4];
#pragma unroll
    for (int mt = 0; mt < 2; ++mt)
#pragma unroll
        for (int nt = 0; nt < 4; ++nt) acc[mt][nt] = (f32x4){0.f, 0.f, 0.f, 0.f};

    auto stage = [&](int kt, int bf) {
        async16(asrc + kt * 64, &As[bf][w * 512]);
#pragma unroll
        for (int q = 0; q < 8; ++q)
            async16(bsrc + (size_t)q * 8192 + kt * 64, &Bs[bf][(w * 64 + q * 8) * 64]);
    };
    auto compute = [&](int bf) {
        const ushort* AB = As[bf];
        const ushort* BB = Bs[bf] + w * 4096;
#pragma unroll
        for (int ks = 0; ks < 2; ++ks) {
            int phys = (((ks * 4 + (L >> 4)) ^ (L & 7))) * 8;
            bf16x8 a0 = *(const bf16x8*)(AB + (L & 15) * 64 + phys);
            bf16x8 a1 = *(const bf16x8*)(AB + (16 + (L & 15)) * 64 + phys);
#pragma unroll
            for (int nt = 0; nt < 4; ++nt) {
                bf16x8 b = *(const bf16x8*)(BB + (nt * 16 + (L & 15)) * 64 + phys);
                acc[0][nt] = __builtin_amdgcn_mfma_f32_16x16x32_bf16(a0, b, acc[0][nt], 0, 0, 0);
                acc[1][nt] = __builtin_amdgcn_mfma_f32_16x16x32_bf16(a1, b, acc[1][nt], 0, 0, 0);
            }
        }
    };

    stage(0, 0);
    for (int t = 0; t < 16; ++t) {
        __syncthreads();                 // drains vmcnt for tile t's global_load_lds
        if (t < 15) stage(t + 1, (t + 1) & 1);
        compute(t & 1);
    }

#pragma unroll
    for (int mt = 0; mt < 2; ++mt)
#pragma unroll
        for (int nt = 0; nt < 4; ++nt) {
            int n = w * 64 + nt * 16 + (L & 15);
#pragma unroll
            for (int r = 0; r < 4; ++r) {
                int m = mt * 16 + (L >> 4) * 4 + r;
                int rowg = rows2[m];
                if (rowg >= 0) {
                    float v = acc[mt][nt][r] * sc_();
                    qp[(size_t)rowg * ED_ + n] = v;
                    union { __bf16 h; ushort u; } cv; cv.h = (__bf16)v;
                    qpb[(size_t)rowg * ED_ + n] = cv.u;
                }
            }
        }
}

// ---------------- rel bias table: rel[bkh,i,p] = q_row . rpe[h,:,p] ----------
__global__ void rel_kernel(const float* __restrict__ qp, const float* __restrict__ rpe,
                           float* __restrict__ rel) {
    int Rr = blockIdx.x * 2 + (threadIdx.x >> 7);
    int p = threadIdx.x & 127;
    int i = Rr & 1023, h = (Rr >> 10) & 3, kk = (Rr >> 12) & 3, bb = Rr >> 14;
    int row = ((i * 2 + bb) << 2) | kk;
    int qbase = __builtin_amdgcn_readfirstlane(row * ED_ + h * HD_);
    int hbase = __builtin_amdgcn_readfirstlane(h * HD_);
    float acc = 0.f;
    for (int d = 0; d < HD_; ++d)
        acc += qp[qbase + d] * rpe[(hbase + d) * 129 + p];
    rel[Rr * 128 + p] = acc;
}

// ---------------- MFMA flash attention (bf16, no-max softmax) ----------------
// block = 256 thr (4 waves), 64 i-rows/block (16/wave), j tiles of 64.
// S^T = K.Q^T (so P round-trips LDS with 8B writes / b128 reads), O^T = V^T.P^T.
__global__ void __launch_bounds__(256)
attn_kernel(const ushort* __restrict__ qpb, const ushort* __restrict__ kpb,
            const ushort* __restrict__ vpT, const float* __restrict__ rel,
            const float* __restrict__ gates, float* __restrict__ az) {
    __shared__ __align__(16) ushort Ks[2][64 * 64];    // [j][d] 8KB x2
    __shared__ __align__(16) ushort Vs[2][64 * 64];    // [d][j] 8KB x2
    __shared__ __align__(16) ushort Ps[4][16 * 64];    // per-wave P [i][j] 2KB x4

    const int tid = threadIdx.x;
    const int w = tid >> 6, L = tid & 63;
    const int bkh = blockIdx.x & 31, it = blockIdx.x >> 5;
    const int h = bkh & 3, kk = (bkh >> 2) & 3, bb = bkh >> 4;
    const int i0w = it * 64 + w * 16;
    const int iL = i0w + (L & 15);
    const int row = ((iL * 2 + bb) << 2) | kk;

    // persistent Q B-frags: B[k=d][n=i], lane: n=L&15, k=(L>>4)*8+jj
    const ushort* qrow = qpb + row * ED_ + h * HD_;
    bf16x8 qf0 = *(const bf16x8*)(qrow + (L >> 4) * 8);
    bf16x8 qf1 = *(const bf16x8*)(qrow + 32 + (L >> 4) * 8);

    const float* relrow = rel + ((size_t)((bkh << 10) + iL)) * 128;
    float rel_lo = relrow[1], rel_hi = relrow[127];
    float gate = gates[row];

    f32x4 O[4];
#pragma unroll
    for (int mf = 0; mf < 4; ++mf) O[mf] = (f32x4){0.f, 0.f, 0.f, 0.f};
    float l_acc = 0.f;

    const ushort* ksrc = kpb + (size_t)(bb << 10) * ED_ + h * HD_;
    const ushort* vsrc = vpT + (size_t)((bb * 4 + h) * 64) * 1024;

    auto stage = [&](int t, int bf) {
        int j0 = t * 64;
#pragma unroll
        for (int q = 0; q < 2; ++q) {
            int r = L >> 3;
            int c = (L & 7) ^ r;
            const ushort* src = ksrc + (size_t)(j0 + w * 16 + q * 8 + r) * ED_ + c * 8;
            async16(src, &Ks[bf][(w * 16 + q * 8) * 64]);
        }
#pragma unroll
        for (int q = 0; q < 2; ++q) {
            int r = L >> 3;
            int d = w * 16 + q * 8 + r;
            int c = (L & 7) ^ (d & 7);
            const ushort* src = vsrc + (size_t)d * 1024 + j0 + c * 8;
            async16(src, &Vs[bf][(w * 16 + q * 8) * 64]);
        }
    };

    auto compute = [&](int bf, int j0) {
        const ushort* KB = Ks[bf];
        const ushort* VB = Vs[bf];
        ushort* PW = Ps[w];
#pragma unroll
        for (int jf = 0; jf < 4; ++jf) {
            int jrow = jf * 16 + (L & 15);
            bf16x8 a0 = *(const bf16x8*)(KB + jrow * 64 + (((L >> 4)) ^ (L & 7)) * 8);
            bf16x8 a1 = *(const bf16x8*)(KB + jrow * 64 + ((4 + (L >> 4)) ^ (L & 7)) * 8);
            f32x4 s = (f32x4){0.f, 0.f, 0.f, 0.f};
            s = __builtin_amdgcn_mfma_f32_16x16x32_bf16(a0, qf0, s, 0, 0, 0);
            s = __builtin_amdgcn_mfma_f32_16x16x32_bf16(a1, qf1, s, 0, 0, 0);
            int jlo = j0 + jf * 16;
            int jbase = jlo + (L >> 4) * 4;
            float pv[4];
            if (jlo >= i0w + 78) {
#pragma unroll
                for (int r = 0; r < 4; ++r) pv[r] = __expf(s[r] + rel_hi);
            } else if (jlo <= i0w - 78) {
#pragma unroll
                for (int r = 0; r < 4; ++r) pv[r] = __expf(s[r] + rel_lo);
            } else {
#pragma unroll
                for (int r = 0; r < 4; ++r) {
                    int dj = jbase + r - iL;
                    dj = dj < -63 ? -63 : (dj > 63 ? 63 : dj);
                    pv[r] = __expf(s[r] + relrow[dj + 64]);
                }
            }
            l_acc += (pv[0] + pv[1]) + (pv[2] + pv[3]);
            union { __bf16 h4[4]; uint2 u; } pk;
#pragma unroll
            for (int r = 0; r < 4; ++r) pk.h4[r] = (__bf16)pv[r];
            int iloc = L & 15;
            int chunk = jf * 2 + ((L >> 4) >> 1);
            int phys = chunk ^ (iloc & 7);
            *(uint2*)(PW + iloc * 64 + phys * 8 + ((L >> 4) & 1) * 4) = pk.u;
        }
#pragma unroll
        for (int ks = 0; ks < 2; ++ks) {
            int c = ks * 4 + (L >> 4);
            int phys = c ^ (L & 7);
            bf16x8 pf = *(const bf16x8*)(PW + (L & 15) * 64 + phys * 8);
#pragma unroll
            for (int mf = 0; mf < 4; ++mf) {
                bf16x8 vf = *(const bf16x8*)(VB + (mf * 16 + (L & 15)) * 64 + phys * 8);
                O[mf] = __builtin_amdgcn_mfma_f32_16x16x32_bf16(vf, pf, O[mf], 0, 0, 0);
            }
        }
    };

    stage(0, 0);
    for (int t = 0; t < 16; ++t) {
        __syncthreads();
        if (t < 15) stage(t + 1, (t + 1) & 1);
        compute(t & 1, t * 64);
    }

    l_acc += __shfl_xor(l_acc, 16);
    l_acc += __shfl_xor(l_acc, 32);
    float inv = gate / l_acc;
    float* azrow = az + (size_t)row * ED_ + h * HD_;
#pragma unroll
    for (int mf = 0; mf < 4; ++mf) {
        f32x4 o = O[mf] * inv;
        *(f32x4*)(azrow + mf * 16 + (L >> 4) * 4) = o;
    }
}

// ---------------- expert reduce: out[n] += az[row] @ w_reduce[e] -------------
// grid = RB_MAX*2 (chunk, d-half), block = 256, 2 cols/thread
__global__ void reduce_kernel(const float* __restrict__ az, const float* __restrict__ wr,
                              const int* __restrict__ perm,
                              const int* __restrict__ rbe, const int* __restrict__ rbs,
                              const int* __restrict__ rbc, float* __restrict__ out) {
    int blk = blockIdx.x >> 1, half = blockIdx.x & 1;
    int nr = rbc[blk];
    if (nr == 0) return;
    int e = rbe[blk], rs = rbs[blk];
    int tid = threadIdx.x;   // 256
    __shared__ __align__(16) float as[16][ED_];
#pragma unroll
    for (int q = 0; q < 16; ++q) {
        int el = tid + q * 256, r = el >> 8, c = el & 255;
        as[r][c] = (r < nr) ? az[(size_t)perm[rs + r] * ED_ + c] : 0.f;
    }
    __syncthreads();
    float2 acc[16];
#pragma unroll
    for (int r = 0; r < 16; ++r) acc[r] = make_float2(0.f, 0.f);
    int d0 = half * 512 + 2 * tid;
    const float* wbase = wr + (size_t)e * (ED_ * D_) + d0;
    for (int c4 = 0; c4 < 64; ++c4) {
        float2 w0 = *(const float2*)(wbase + (size_t)(c4 * 4 + 0) * D_);
        float2 w1 = *(const float2*)(wbase + (size_t)(c4 * 4 + 1) * D_);
        float2 w2 = *(const float2*)(wbase + (size_t)(c4 * 4 + 2) * D_);
        float2 w3 = *(const float2*)(wbase + (size_t)(c4 * 4 + 3) * D_);
#pragma unroll
        for (int r = 0; r < 16; ++r) {
            float4 a4 = *(const float4*)&as[r][c4 * 4];
            acc[r].x += a4.x * w0.x + a4.y * w1.x + a4.z * w2.x + a4.w * w3.x;
            acc[r].y += a4.x * w0.y + a4.y * w1.y + a4.z * w2.y + a4.w * w3.y;
        }
    }
    for (int r = 0; r < nr; ++r) {
        int n = perm[rs + r] >> 2;
        float* op = out + (size_t)n * D_ + d0;
        atomicAdd(op + 0, acc[r].x);
        atomicAdd(op + 1, acc[r].y);
    }
}

// ---------------- launcher ---------------------------------------------------
extern "C" void kernel_launch(void* const* d_in, const int* in_sizes, int n_in,
                              void* d_out, int out_size, void* d_ws, size_t ws_size,
                              hipStream_t stream) {
    const float* query = (const float*)d_in[0];
    const float* key   = (const float*)d_in[1];
    const float* value = (const float*)d_in[2];
    const float* wg    = (const float*)d_in[3];
    const float* wmap  = (const float*)d_in[4];
    const float* wred  = (const float*)d_in[5];
    const float* wk    = (const float*)d_in[6];
    const float* wv    = (const float*)d_in[7];
    const float* rpe   = (const float*)d_in[8];
    float* out = (float*)d_out;

    char* ws = (char*)d_ws;
    float*  gates = (float*)(ws + 0);                      // 32 KB
    int*    idx   = (int*)(ws + (32 << 10));               // 32 KB
    char*   misc  = ws + (64 << 10);
    int*    counts = (int*)(misc + 0);                     // [zeroed]
    int*    cur    = (int*)(misc + 64);                    // [zeroed]
    int*    offs   = (int*)(misc + 128);
    int*    rbe    = (int*)(misc + 256);
    int*    rbs    = (int*)(misc + 2560);
    int*    rbc    = (int*)(misc + 4864);
    int*    rbe2   = (int*)(misc + 8192);
    int*    rbs2   = (int*)(misc + 9472);
    int*    rbc2   = (int*)(misc + 10752);
    int*    perm  = (int*)(ws + (96 << 10));               // 32 KB
    float*  qp    = (float*)(ws + (128 << 10));            // 8 MB  f32 (rel input)
    ushort* qpb   = (ushort*)(ws + (128 << 10) + (8u  << 20));  // 4 MB bf16
    ushort* kpb   = (ushort*)(ws + (128 << 10) + (12u << 20)); // 1 MB bf16 [b][t][ed]
    ushort* vpT   = (ushort*)(ws + (128 << 10) + (13u << 20)); // 1 MB bf16 [b][h][d][t]
    float*  rel   = (float*)(ws + (128 << 10) + (14u << 20));  // 16 MB
    float*  az    = (float*)(ws + (128 << 10) + (30u << 20));  // 8 MB
    ushort* xb    = (ushort*)(ws + (128 << 10) + (38u << 20)); // 4 MB bf16 tokens
    ushort* wmapT = (ushort*)(ws + (128 << 10) + (42u << 20)); // 6 MB bf16 [e][ed][d]

    hipMemsetAsync(misc, 0, 128, stream);
    hipMemsetAsync(out, 0, (size_t)out_size * sizeof(float), stream);

    castx_kernel<<<(N_ * D_) / 1024, 256, 0, stream>>>(query, xb);
    castw_kernel<<<dim3(E_, 16, 4), 256, 0, stream>>>(wmap, wmapT);
    gate_kernel<<<N_, 64, 0, stream>>>(query, wg, gates, idx, counts);
    scan_kernel<<<1, 64, 0, stream>>>(counts, offs, rbe, rbs, rbc, rbe2, rbs2, rbc2);
    scatter_kernel<<<NROW / 256, 256, 0, stream>>>(idx, offs, cur, perm);
    kv_kernel<<<dim3(N_ / 8, 2), 128, 0, stream>>>(key, value, wk, wv, kpb, vpT);
    qproj_mfma<<<PB_MAX, 256, 0, stream>>>(xb, wmapT, perm, rbe2, rbs2, rbc2, qp, qpb);
    rel_kernel<<<(32 * T_) / 2, 256, 0, stream>>>(qp, rpe, rel);
    attn_kernel<<<512, 256, 0, stream>>>(qpb, kpb, vpT, rel, gates, az);
    reduce_kernel<<<RB_MAX * 2, 256, 0, stream>>>(az, wred, perm, rbe, rbs, rbc, out);
}

// Round 4
// 503.675 us; speedup vs baseline: 3.1410x; 1.1613x over previous
//
#include <hip/hip_runtime.h>

#define T_    1024
#define B_    2
#define D_    1024
#define E_    12
#define TOPK  4
#define ED_   256
#define HD_   64
#define H_    4
#define N_    (T_*B_)      // 2048 tokens
#define NROW  (N_*TOPK)    // 8192 (n,k) rows
#define RB_MAX 524         // max 16-row expert chunks: 8192/16 + 12
#define PB_MAX 268         // max 32-row expert chunks: 8192/32 + 12

typedef __bf16 bf16x8 __attribute__((ext_vector_type(8)));
typedef float  f32x4  __attribute__((ext_vector_type(4)));

__device__ __forceinline__ float sc_() { return 0.35355339059327373f; } // 64^-0.25

__device__ __forceinline__ void async16(const void* g, void* l) {
    __builtin_amdgcn_global_load_lds((const __attribute__((address_space(1))) void*)g,
                                     (__attribute__((address_space(3))) void*)l, 16, 0, 0);
}

// ---------------- gating: logits -> softmax -> top4 + expert counts ----------
__global__ void gate_kernel(const float* __restrict__ x, const float* __restrict__ wg,
                            float* __restrict__ gates, int* __restrict__ idx,
                            int* __restrict__ counts) {
    int n = blockIdx.x, t = threadIdx.x;   // block = 64 (one wave) per token
    float part[E_];
#pragma unroll
    for (int e = 0; e < E_; ++e) part[e] = 0.f;
    for (int m = 0; m < D_ / 64; ++m) {
        float xv = x[n * D_ + m * 64 + t];
        const float* wr = wg + (m * 64 + t) * E_;
#pragma unroll
        for (int e = 0; e < E_; ++e) part[e] += xv * wr[e];
    }
#pragma unroll
    for (int e = 0; e < E_; ++e) {
        float v = part[e];
        for (int o = 32; o > 0; o >>= 1) v += __shfl_down(v, o);
        part[e] = v;
    }
    if (t == 0) {
        float mx = part[0];
        for (int e = 1; e < E_; ++e) mx = fmaxf(mx, part[e]);
        float s = 0.f, pr[E_];
        for (int e = 0; e < E_; ++e) { pr[e] = expf(part[e] - mx); s += pr[e]; }
        float inv = 1.f / s;
        for (int e = 0; e < E_; ++e) pr[e] *= inv;
        for (int k = 0; k < TOPK; ++k) {
            int be = 0; float bv = -1.f;
            for (int e = 0; e < E_; ++e) if (pr[e] > bv) { bv = pr[e]; be = e; }
            gates[n * TOPK + k] = bv;
            idx[n * TOPK + k] = be;
            pr[be] = -1.f;
            atomicAdd(&counts[be], 1);
        }
    }
}

// ---------------- scan: offsets + 16-row and 32-row expert chunk maps --------
__global__ void scan_kernel(const int* __restrict__ counts, int* __restrict__ offs,
                            int* __restrict__ rbe, int* __restrict__ rbs, int* __restrict__ rbc,
                            int* __restrict__ rbe2, int* __restrict__ rbs2, int* __restrict__ rbc2) {
    if (threadIdx.x == 0 && blockIdx.x == 0) {
        int o = 0;
        for (int e = 0; e < E_; ++e) { offs[e] = o; o += counts[e]; }
        offs[E_] = o;
        int nb = 0;
        for (int e = 0; e < E_; ++e) {
            int c = counts[e];
            for (int s = 0; s < c; s += 16) {
                rbe[nb] = e; rbs[nb] = offs[e] + s;
                rbc[nb] = (c - s < 16) ? (c - s) : 16; ++nb;
            }
        }
        for (; nb < RB_MAX; ++nb) { rbe[nb] = 0; rbs[nb] = 0; rbc[nb] = 0; }
        int nb2 = 0;
        for (int e = 0; e < E_; ++e) {
            int c = counts[e];
            for (int s = 0; s < c; s += 32) {
                rbe2[nb2] = e; rbs2[nb2] = offs[e] + s;
                rbc2[nb2] = (c - s < 32) ? (c - s) : 32; ++nb2;
            }
        }
        for (; nb2 < PB_MAX; ++nb2) { rbe2[nb2] = 0; rbs2[nb2] = 0; rbc2[nb2] = 0; }
    }
}

// ---------------- scatter rows into expert-grouped perm ----------------------
__global__ void scatter_kernel(const int* __restrict__ idx, const int* __restrict__ offs,
                               int* __restrict__ cur, int* __restrict__ perm) {
    int r = blockIdx.x * 256 + threadIdx.x;   // 8192 rows
    int e = idx[r];
    int p = atomicAdd(&cur[e], 1);
    perm[offs[e] + p] = r;
}

// ---------------- one-time casts ---------------------------------------------
__global__ void castx_kernel(const float* __restrict__ x, ushort* __restrict__ xb) {
    int t = blockIdx.x * 256 + threadIdx.x;
    float4 v = *(const float4*)(x + (size_t)t * 4);
    union { __bf16 h[4]; uint2 u; } pk;
    pk.h[0] = (__bf16)v.x; pk.h[1] = (__bf16)v.y;
    pk.h[2] = (__bf16)v.z; pk.h[3] = (__bf16)v.w;
    *(uint2*)(xb + (size_t)t * 4) = pk.u;
}

// grid (12,16,4): e, 64-d tile, 64-ed tile.  wmapT[e][ed][d] = bf16(w_map[e][d][ed])
__global__ void castw_kernel(const float* __restrict__ wmap, ushort* __restrict__ wmapT) {
    int e = blockIdx.x, dt = blockIdx.y, et = blockIdx.z;
    __shared__ float ls[64][65];
    int c = threadIdx.x & 63, rg = threadIdx.x >> 6;
    const float* src = wmap + (size_t)e * (D_ * ED_) + (size_t)(dt * 64) * ED_ + et * 64;
#pragma unroll
    for (int q = 0; q < 16; ++q) {
        int r = q * 4 + rg;
        ls[r][c] = src[(size_t)r * ED_ + c];
    }
    __syncthreads();
    ushort* dst = wmapT + ((size_t)e << 18) + (size_t)(et * 64) * 1024 + dt * 64;
#pragma unroll
    for (int q = 0; q < 16; ++q) {
        int r = q * 4 + rg;
        union { __bf16 h; ushort u; } cv; cv.h = (__bf16)ls[c][r];
        dst[(size_t)r * 1024 + c] = cv.u;
    }
}

// grid (2,16,4): which, 64-d tile, 64-ed tile. wT[ed][d] = bf16(w[d][ed])
__global__ void castwkv_kernel(const float* __restrict__ wk, const float* __restrict__ wv,
                               ushort* __restrict__ wkT, ushort* __restrict__ wvT) {
    int which = blockIdx.x, dt = blockIdx.y, et = blockIdx.z;
    const float* w = which ? wv : wk;
    ushort* wT = which ? wvT : wkT;
    __shared__ float ls[64][65];
    int c = threadIdx.x & 63, rg = threadIdx.x >> 6;
    const float* src = w + (size_t)(dt * 64) * ED_ + et * 64;
#pragma unroll
    for (int q = 0; q < 16; ++q) {
        int r = q * 4 + rg;
        ls[r][c] = src[(size_t)r * ED_ + c];
    }
    __syncthreads();
    ushort* dst = wT + (size_t)(et * 64) * 1024 + dt * 64;
#pragma unroll
    for (int q = 0; q < 16; ++q) {
        int r = q * 4 + rg;
        union { __bf16 h; ushort u; } cv; cv.h = (__bf16)ls[c][r];
        dst[(size_t)r * 1024 + c] = cv.u;
    }
}

// ---------------- k/v projection as bf16 MFMA GEMM ---------------------------
// grid (64, 2): M-tile of 32 rows (m-order = b*1024+t), which (K / V)
// block = 256 thr (4 waves), N=256 (wave w: cols w*64..+63), K=1024, BK=64 dbuf
__global__ void __launch_bounds__(256)
kv_mfma(const ushort* __restrict__ keyb, const ushort* __restrict__ valb,
        const ushort* __restrict__ wkT, const ushort* __restrict__ wvT,
        ushort* __restrict__ kpb, ushort* __restrict__ vpT) {
    int which = blockIdx.y;
    const ushort* xb = which ? valb : keyb;
    const ushort* wT = which ? wvT : wkT;
    int m0 = blockIdx.x * 32;
    int b = m0 >> 10, t0 = m0 & 1023;
    int tid = threadIdx.x, w = tid >> 6, L = tid & 63;
    __shared__ __align__(16) ushort As[2][32 * 64];       // 4 KB x2
    __shared__ __align__(16) ushort Bs[2][4 * 64 * 64];   // 32 KB x2

    int swz = ((L & 7) ^ ((L >> 3) & 7)) * 8;
    int an = (((t0 + w * 8 + (L >> 3)) << 1) | b);        // token row for A staging
    const ushort* asrc = xb + (size_t)an * 1024 + swz;
    const ushort* bsrc = wT + (size_t)(w * 64 + (L >> 3)) * 1024 + swz;

    f32x4 acc[2][4];
#pragma unroll
    for (int mt = 0; mt < 2; ++mt)
#pragma unroll
        for (int nt = 0; nt < 4; ++nt) acc[mt][nt] = (f32x4){0.f, 0.f, 0.f, 0.f};

    auto stage = [&](int kt, int bf) {
        async16(asrc + kt * 64, &As[bf][w * 512]);
#pragma unroll
        for (int q = 0; q < 8; ++q)
            async16(bsrc + (size_t)q * 8192 + kt * 64, &Bs[bf][(w * 64 + q * 8) * 64]);
    };
    auto compute = [&](int bf) {
        const ushort* AB = As[bf];
        const ushort* BB = Bs[bf] + w * 4096;
#pragma unroll
        for (int ks = 0; ks < 2; ++ks) {
            int phys = (((ks * 4 + (L >> 4)) ^ (L & 7))) * 8;
            bf16x8 a0 = *(const bf16x8*)(AB + (L & 15) * 64 + phys);
            bf16x8 a1 = *(const bf16x8*)(AB + (16 + (L & 15)) * 64 + phys);
#pragma unroll
            for (int nt = 0; nt < 4; ++nt) {
                bf16x8 bfr = *(const bf16x8*)(BB + (nt * 16 + (L & 15)) * 64 + phys);
                acc[0][nt] = __builtin_amdgcn_mfma_f32_16x16x32_bf16(a0, bfr, acc[0][nt], 0, 0, 0);
                acc[1][nt] = __builtin_amdgcn_mfma_f32_16x16x32_bf16(a1, bfr, acc[1][nt], 0, 0, 0);
            }
        }
    };

    stage(0, 0);
    for (int t = 0; t < 16; ++t) {
        __syncthreads();
        if (t < 15) stage(t + 1, (t + 1) & 1);
        compute(t & 1);
    }

#pragma unroll
    for (int mt = 0; mt < 2; ++mt)
#pragma unroll
        for (int nt = 0; nt < 4; ++nt) {
            int ed = w * 64 + nt * 16 + (L & 15);
            int tb = t0 + mt * 16 + (L >> 4) * 4;        // first of 4 consecutive t
            if (which == 0) {
#pragma unroll
                for (int r = 0; r < 4; ++r) {
                    union { __bf16 h; ushort u; } cv;
                    cv.h = (__bf16)(acc[mt][nt][r] * sc_());
                    kpb[((size_t)((b << 10) + tb + r)) * ED_ + ed] = cv.u;
                }
            } else {
                int h = ed >> 6, d = ed & 63;
                union { __bf16 h4[4]; uint2 u; } pk;
#pragma unroll
                for (int r = 0; r < 4; ++r) pk.h4[r] = (__bf16)acc[mt][nt][r];
                *(uint2*)&vpT[((size_t)((b * 4 + h) * 64 + d)) * 1024 + tb] = pk.u;
            }
        }
}

// ---------------- q projection as bf16 MFMA GEMM per 32-row expert chunk -----
__global__ void __launch_bounds__(256)
qproj_mfma(const ushort* __restrict__ xb, const ushort* __restrict__ wmapT,
           const int* __restrict__ perm,
           const int* __restrict__ rbe2, const int* __restrict__ rbs2,
           const int* __restrict__ rbc2,
           float* __restrict__ qp, ushort* __restrict__ qpb) {
    int blk = blockIdx.x;
    int nr = rbc2[blk];
    if (nr == 0) return;
    int e = rbe2[blk], rs = rbs2[blk];
    int tid = threadIdx.x, w = tid >> 6, L = tid & 63;
    __shared__ __align__(16) ushort As[2][32 * 64];
    __shared__ __align__(16) ushort Bs[2][4 * 64 * 64];
    __shared__ int rows2[32];
    if (tid < 32) rows2[tid] = (tid < nr) ? perm[rs + tid] : -1;
    __syncthreads();

    int swz = ((L & 7) ^ ((L >> 3) & 7)) * 8;
    int ar = rows2[w * 8 + (L >> 3)];
    const ushort* asrc = xb + (size_t)((ar < 0 ? 0 : ar) >> 2) * 1024 + swz;
    const ushort* bsrc = wmapT + ((size_t)e << 18) + (size_t)(w * 64 + (L >> 3)) * 1024 + swz;

    f32x4 acc[2][4];
#pragma unroll
    for (int mt = 0; mt < 2; ++mt)
#pragma unroll
        for (int nt = 0; nt < 4; ++nt) acc[mt][nt] = (f32x4){0.f, 0.f, 0.f, 0.f};

    auto stage = [&](int kt, int bf) {
        async16(asrc + kt * 64, &As[bf][w * 512]);
#pragma unroll
        for (int q = 0; q < 8; ++q)
            async16(bsrc + (size_t)q * 8192 + kt * 64, &Bs[bf][(w * 64 + q * 8) * 64]);
    };
    auto compute = [&](int bf) {
        const ushort* AB = As[bf];
        const ushort* BB = Bs[bf] + w * 4096;
#pragma unroll
        for (int ks = 0; ks < 2; ++ks) {
            int phys = (((ks * 4 + (L >> 4)) ^ (L & 7))) * 8;
            bf16x8 a0 = *(const bf16x8*)(AB + (L & 15) * 64 + phys);
            bf16x8 a1 = *(const bf16x8*)(AB + (16 + (L & 15)) * 64 + phys);
#pragma unroll
            for (int nt = 0; nt < 4; ++nt) {
                bf16x8 b = *(const bf16x8*)(BB + (nt * 16 + (L & 15)) * 64 + phys);
                acc[0][nt] = __builtin_amdgcn_mfma_f32_16x16x32_bf16(a0, b, acc[0][nt], 0, 0, 0);
                acc[1][nt] = __builtin_amdgcn_mfma_f32_16x16x32_bf16(a1, b, acc[1][nt], 0, 0, 0);
            }
        }
    };

    stage(0, 0);
    for (int t = 0; t < 16; ++t) {
        __syncthreads();
        if (t < 15) stage(t + 1, (t + 1) & 1);
        compute(t & 1);
    }

#pragma unroll
    for (int mt = 0; mt < 2; ++mt)
#pragma unroll
        for (int nt = 0; nt < 4; ++nt) {
            int n = w * 64 + nt * 16 + (L & 15);
#pragma unroll
            for (int r = 0; r < 4; ++r) {
                int m = mt * 16 + (L >> 4) * 4 + r;
                int rowg = rows2[m];
                if (rowg >= 0) {
                    float v = acc[mt][nt][r] * sc_();
                    qp[(size_t)rowg * ED_ + n] = v;
                    union { __bf16 h; ushort u; } cv; cv.h = (__bf16)v;
                    qpb[(size_t)rowg * ED_ + n] = cv.u;
                }
            }
        }
}

// ---------------- rel bias table: rel[bkh,i,p] = q_row . rpe[h,:,p] ----------
__global__ void rel_kernel(const float* __restrict__ qp, const float* __restrict__ rpe,
                           float* __restrict__ rel) {
    int Rr = blockIdx.x * 2 + (threadIdx.x >> 7);
    int p = threadIdx.x & 127;
    int i = Rr & 1023, h = (Rr >> 10) & 3, kk = (Rr >> 12) & 3, bb = Rr >> 14;
    int row = ((i * 2 + bb) << 2) | kk;
    int qbase = __builtin_amdgcn_readfirstlane(row * ED_ + h * HD_);
    int hbase = __builtin_amdgcn_readfirstlane(h * HD_);
    float acc = 0.f;
    for (int d = 0; d < HD_; ++d)
        acc += qp[qbase + d] * rpe[(hbase + d) * 129 + p];
    rel[Rr * 128 + p] = acc;
}

// ---------------- MFMA flash attention (bf16, no-max softmax) ----------------
__global__ void __launch_bounds__(256)
attn_kernel(const ushort* __restrict__ qpb, const ushort* __restrict__ kpb,
            const ushort* __restrict__ vpT, const float* __restrict__ rel,
            const float* __restrict__ gates, float* __restrict__ az) {
    __shared__ __align__(16) ushort Ks[2][64 * 64];    // [j][d] 8KB x2
    __shared__ __align__(16) ushort Vs[2][64 * 64];    // [d][j] 8KB x2
    __shared__ __align__(16) ushort Ps[4][16 * 64];    // per-wave P [i][j] 2KB x4

    const int tid = threadIdx.x;
    const int w = tid >> 6, L = tid & 63;
    const int bkh = blockIdx.x & 31, it = blockIdx.x >> 5;
    const int h = bkh & 3, kk = (bkh >> 2) & 3, bb = bkh >> 4;
    const int i0w = it * 64 + w * 16;
    const int iL = i0w + (L & 15);
    const int row = ((iL * 2 + bb) << 2) | kk;

    const ushort* qrow = qpb + row * ED_ + h * HD_;
    bf16x8 qf0 = *(const bf16x8*)(qrow + (L >> 4) * 8);
    bf16x8 qf1 = *(const bf16x8*)(qrow + 32 + (L >> 4) * 8);

    const float* relrow = rel + ((size_t)((bkh << 10) + iL)) * 128;
    float rel_lo = relrow[1], rel_hi = relrow[127];
    float gate = gates[row];

    f32x4 O[4];
#pragma unroll
    for (int mf = 0; mf < 4; ++mf) O[mf] = (f32x4){0.f, 0.f, 0.f, 0.f};
    float l_acc = 0.f;

    const ushort* ksrc = kpb + (size_t)(bb << 10) * ED_ + h * HD_;
    const ushort* vsrc = vpT + (size_t)((bb * 4 + h) * 64) * 1024;

    auto stage = [&](int t, int bf) {
        int j0 = t * 64;
#pragma unroll
        for (int q = 0; q < 2; ++q) {
            int r = L >> 3;
            int c = (L & 7) ^ r;
            const ushort* src = ksrc + (size_t)(j0 + w * 16 + q * 8 + r) * ED_ + c * 8;
            async16(src, &Ks[bf][(w * 16 + q * 8) * 64]);
        }
#pragma unroll
        for (int q = 0; q < 2; ++q) {
            int r = L >> 3;
            int d = w * 16 + q * 8 + r;
            int c = (L & 7) ^ (d & 7);
            const ushort* src = vsrc + (size_t)d * 1024 + j0 + c * 8;
            async16(src, &Vs[bf][(w * 16 + q * 8) * 64]);
        }
    };

    auto compute = [&](int bf, int j0) {
        const ushort* KB = Ks[bf];
        const ushort* VB = Vs[bf];
        ushort* PW = Ps[w];
#pragma unroll
        for (int jf = 0; jf < 4; ++jf) {
            int jrow = jf * 16 + (L & 15);
            bf16x8 a0 = *(const bf16x8*)(KB + jrow * 64 + (((L >> 4)) ^ (L & 7)) * 8);
            bf16x8 a1 = *(const bf16x8*)(KB + jrow * 64 + ((4 + (L >> 4)) ^ (L & 7)) * 8);
            f32x4 s = (f32x4){0.f, 0.f, 0.f, 0.f};
            s = __builtin_amdgcn_mfma_f32_16x16x32_bf16(a0, qf0, s, 0, 0, 0);
            s = __builtin_amdgcn_mfma_f32_16x16x32_bf16(a1, qf1, s, 0, 0, 0);
            int jlo = j0 + jf * 16;
            int jbase = jlo + (L >> 4) * 4;
            float pv[4];
            if (jlo >= i0w + 78) {
#pragma unroll
                for (int r = 0; r < 4; ++r) pv[r] = __expf(s[r] + rel_hi);
            } else if (jlo <= i0w - 78) {
#pragma unroll
                for (int r = 0; r < 4; ++r) pv[r] = __expf(s[r] + rel_lo);
            } else {
#pragma unroll
                for (int r = 0; r < 4; ++r) {
                    int dj = jbase + r - iL;
                    dj = dj < -63 ? -63 : (dj > 63 ? 63 : dj);
                    pv[r] = __expf(s[r] + relrow[dj + 64]);
                }
            }
            l_acc += (pv[0] + pv[1]) + (pv[2] + pv[3]);
            union { __bf16 h4[4]; uint2 u; } pk;
#pragma unroll
            for (int r = 0; r < 4; ++r) pk.h4[r] = (__bf16)pv[r];
            int iloc = L & 15;
            int chunk = jf * 2 + ((L >> 4) >> 1);
            int phys = chunk ^ (iloc & 7);
            *(uint2*)(PW + iloc * 64 + phys * 8 + ((L >> 4) & 1) * 4) = pk.u;
        }
#pragma unroll
        for (int ks = 0; ks < 2; ++ks) {
            int c = ks * 4 + (L >> 4);
            int phys = c ^ (L & 7);
            bf16x8 pf = *(const bf16x8*)(PW + (L & 15) * 64 + phys * 8);
#pragma unroll
            for (int mf = 0; mf < 4; ++mf) {
                bf16x8 vf = *(const bf16x8*)(VB + (mf * 16 + (L & 15)) * 64 + phys * 8);
                O[mf] = __builtin_amdgcn_mfma_f32_16x16x32_bf16(vf, pf, O[mf], 0, 0, 0);
            }
        }
    };

    stage(0, 0);
    for (int t = 0; t < 16; ++t) {
        __syncthreads();
        if (t < 15) stage(t + 1, (t + 1) & 1);
        compute(t & 1, t * 64);
    }

    l_acc += __shfl_xor(l_acc, 16);
    l_acc += __shfl_xor(l_acc, 32);
    float inv = gate / l_acc;
    float* azrow = az + (size_t)row * ED_ + h * HD_;
#pragma unroll
    for (int mf = 0; mf < 4; ++mf) {
        f32x4 o = O[mf] * inv;
        *(f32x4*)(azrow + mf * 16 + (L >> 4) * 4) = o;
    }
}

// ---------------- expert reduce: out[n] += az[row] @ w_reduce[e] -------------
__global__ void reduce_kernel(const float* __restrict__ az, const float* __restrict__ wr,
                              const int* __restrict__ perm,
                              const int* __restrict__ rbe, const int* __restrict__ rbs,
                              const int* __restrict__ rbc, float* __restrict__ out) {
    int blk = blockIdx.x >> 1, half = blockIdx.x & 1;
    int nr = rbc[blk];
    if (nr == 0) return;
    int e = rbe[blk], rs = rbs[blk];
    int tid = threadIdx.x;   // 256
    __shared__ __align__(16) float as[16][ED_];
#pragma unroll
    for (int q = 0; q < 16; ++q) {
        int el = tid + q * 256, r = el >> 8, c = el & 255;
        as[r][c] = (r < nr) ? az[(size_t)perm[rs + r] * ED_ + c] : 0.f;
    }
    __syncthreads();
    float2 acc[16];
#pragma unroll
    for (int r = 0; r < 16; ++r) acc[r] = make_float2(0.f, 0.f);
    int d0 = half * 512 + 2 * tid;
    const float* wbase = wr + (size_t)e * (ED_ * D_) + d0;
    for (int c4 = 0; c4 < 64; ++c4) {
        float2 w0 = *(const float2*)(wbase + (size_t)(c4 * 4 + 0) * D_);
        float2 w1 = *(const float2*)(wbase + (size_t)(c4 * 4 + 1) * D_);
        float2 w2 = *(const float2*)(wbase + (size_t)(c4 * 4 + 2) * D_);
        float2 w3 = *(const float2*)(wbase + (size_t)(c4 * 4 + 3) * D_);
#pragma unroll
        for (int r = 0; r < 16; ++r) {
            float4 a4 = *(const float4*)&as[r][c4 * 4];
            acc[r].x += a4.x * w0.x + a4.y * w1.x + a4.z * w2.x + a4.w * w3.x;
            acc[r].y += a4.x * w0.y + a4.y * w1.y + a4.z * w2.y + a4.w * w3.y;
        }
    }
    for (int r = 0; r < nr; ++r) {
        int n = perm[rs + r] >> 2;
        float* op = out + (size_t)n * D_ + d0;
        atomicAdd(op + 0, acc[r].x);
        atomicAdd(op + 1, acc[r].y);
    }
}

// ---------------- launcher ---------------------------------------------------
extern "C" void kernel_launch(void* const* d_in, const int* in_sizes, int n_in,
                              void* d_out, int out_size, void* d_ws, size_t ws_size,
                              hipStream_t stream) {
    const float* query = (const float*)d_in[0];
    const float* key   = (const float*)d_in[1];
    const float* value = (const float*)d_in[2];
    const float* wg    = (const float*)d_in[3];
    const float* wmap  = (const float*)d_in[4];
    const float* wred  = (const float*)d_in[5];
    const float* wk    = (const float*)d_in[6];
    const float* wv    = (const float*)d_in[7];
    const float* rpe   = (const float*)d_in[8];
    float* out = (float*)d_out;

    char* ws = (char*)d_ws;
    float*  gates = (float*)(ws + 0);                      // 32 KB
    int*    idx   = (int*)(ws + (32 << 10));               // 32 KB
    char*   misc  = ws + (64 << 10);
    int*    counts = (int*)(misc + 0);                     // [zeroed]
    int*    cur    = (int*)(misc + 64);                    // [zeroed]
    int*    offs   = (int*)(misc + 128);
    int*    rbe    = (int*)(misc + 256);
    int*    rbs    = (int*)(misc + 2560);
    int*    rbc    = (int*)(misc + 4864);
    int*    rbe2   = (int*)(misc + 8192);
    int*    rbs2   = (int*)(misc + 9472);
    int*    rbc2   = (int*)(misc + 10752);
    int*    perm  = (int*)(ws + (96 << 10));               // 32 KB
    float*  qp    = (float*)(ws + (128 << 10));            // 8 MB  f32 (rel input)
    ushort* qpb   = (ushort*)(ws + (128 << 10) + (8u  << 20));  // 4 MB bf16
    ushort* kpb   = (ushort*)(ws + (128 << 10) + (12u << 20)); // 1 MB bf16 [b][t][ed]
    ushort* vpT   = (ushort*)(ws + (128 << 10) + (13u << 20)); // 1 MB bf16 [b][h][d][t]
    float*  rel   = (float*)(ws + (128 << 10) + (14u << 20));  // 16 MB
    float*  az    = (float*)(ws + (128 << 10) + (30u << 20));  // 8 MB
    ushort* xb    = (ushort*)(ws + (128 << 10) + (38u << 20)); // 4 MB bf16 query
    ushort* wmapT = (ushort*)(ws + (128 << 10) + (42u << 20)); // 6 MB bf16 [e][ed][d]
    ushort* keyb  = (ushort*)(ws + (128 << 10) + (48u << 20)); // 4 MB bf16 key
    ushort* valb  = (ushort*)(ws + (128 << 10) + (52u << 20)); // 4 MB bf16 value
    ushort* wkT   = (ushort*)(ws + (128 << 10) + (56u << 20)); // 0.5 MB
    ushort* wvT   = (ushort*)(ws + (128 << 10) + (57u << 20)); // 0.5 MB

    hipMemsetAsync(misc, 0, 128, stream);
    hipMemsetAsync(out, 0, (size_t)out_size * sizeof(float), stream);

    castx_kernel<<<(N_ * D_) / 1024, 256, 0, stream>>>(query, xb);
    castx_kernel<<<(N_ * D_) / 1024, 256, 0, stream>>>(key, keyb);
    castx_kernel<<<(N_ * D_) / 1024, 256, 0, stream>>>(value, valb);
    castw_kernel<<<dim3(E_, 16, 4), 256, 0, stream>>>(wmap, wmapT);
    castwkv_kernel<<<dim3(2, 16, 4), 256, 0, stream>>>(wk, wv, wkT, wvT);
    gate_kernel<<<N_, 64, 0, stream>>>(query, wg, gates, idx, counts);
    scan_kernel<<<1, 64, 0, stream>>>(counts, offs, rbe, rbs, rbc, rbe2, rbs2, rbc2);
    scatter_kernel<<<NROW / 256, 256, 0, stream>>>(idx, offs, cur, perm);
    kv_mfma<<<dim3(64, 2), 256, 0, stream>>>(keyb, valb, wkT, wvT, kpb, vpT);
    qproj_mfma<<<PB_MAX, 256, 0, stream>>>(xb, wmapT, perm, rbe2, rbs2, rbc2, qp, qpb);
    rel_kernel<<<(32 * T_) / 2, 256, 0, stream>>>(qp, rpe, rel);
    attn_kernel<<<512, 256, 0, stream>>>(qpb, kpb, vpT, rel, gates, az);
    reduce_kernel<<<RB_MAX * 2, 256, 0, stream>>>(az, wred, perm, rbe, rbs, rbc, out);
}

// Round 5
// 414.494 us; speedup vs baseline: 3.8168x; 1.2152x over previous
//
#include <hip/hip_runtime.h>

#define T_    1024
#define B_    2
#define D_    1024
#define E_    12
#define TOPK  4
#define ED_   256
#define HD_   64
#define H_    4
#define N_    (T_*B_)      // 2048 tokens
#define NROW  (N_*TOPK)    // 8192 (n,k) rows
#define PB_MAX 268         // max 32-row expert chunks: 8192/32 + 12
#define KR_   768          // split-precision K for reduce: [a_hi|a_lo|a_hi]

typedef __bf16 bf16x8 __attribute__((ext_vector_type(8)));
typedef float  f32x4  __attribute__((ext_vector_type(4)));

__device__ __forceinline__ float sc_() { return 0.35355339059327373f; } // 64^-0.25

__device__ __forceinline__ void async16(const void* g, void* l) {
    __builtin_amdgcn_global_load_lds((const __attribute__((address_space(1))) void*)g,
                                     (__attribute__((address_space(3))) void*)l, 16, 0, 0);
}

// ---------------- gating: logits -> softmax -> top4 + expert counts ----------
__global__ void gate_kernel(const float* __restrict__ x, const float* __restrict__ wg,
                            float* __restrict__ gates, int* __restrict__ idx,
                            int* __restrict__ counts) {
    int n = blockIdx.x, t = threadIdx.x;   // block = 64 (one wave) per token
    float part[E_];
#pragma unroll
    for (int e = 0; e < E_; ++e) part[e] = 0.f;
    for (int m = 0; m < D_ / 64; ++m) {
        float xv = x[n * D_ + m * 64 + t];
        const float* wr = wg + (m * 64 + t) * E_;
#pragma unroll
        for (int e = 0; e < E_; ++e) part[e] += xv * wr[e];
    }
#pragma unroll
    for (int e = 0; e < E_; ++e) {
        float v = part[e];
        for (int o = 32; o > 0; o >>= 1) v += __shfl_down(v, o);
        part[e] = v;
    }
    if (t == 0) {
        float mx = part[0];
        for (int e = 1; e < E_; ++e) mx = fmaxf(mx, part[e]);
        float s = 0.f, pr[E_];
        for (int e = 0; e < E_; ++e) { pr[e] = expf(part[e] - mx); s += pr[e]; }
        float inv = 1.f / s;
        for (int e = 0; e < E_; ++e) pr[e] *= inv;
        for (int k = 0; k < TOPK; ++k) {
            int be = 0; float bv = -1.f;
            for (int e = 0; e < E_; ++e) if (pr[e] > bv) { bv = pr[e]; be = e; }
            gates[n * TOPK + k] = bv;
            idx[n * TOPK + k] = be;
            pr[be] = -1.f;
            atomicAdd(&counts[be], 1);
        }
    }
}

// ---------------- scan: offsets + 32-row expert chunk map --------------------
__global__ void scan_kernel(const int* __restrict__ counts, int* __restrict__ offs,
                            int* __restrict__ rbe2, int* __restrict__ rbs2, int* __restrict__ rbc2) {
    if (threadIdx.x == 0 && blockIdx.x == 0) {
        int o = 0;
        for (int e = 0; e < E_; ++e) { offs[e] = o; o += counts[e]; }
        offs[E_] = o;
        int nb2 = 0;
        for (int e = 0; e < E_; ++e) {
            int c = counts[e];
            for (int s = 0; s < c; s += 32) {
                rbe2[nb2] = e; rbs2[nb2] = offs[e] + s;
                rbc2[nb2] = (c - s < 32) ? (c - s) : 32; ++nb2;
            }
        }
        for (; nb2 < PB_MAX; ++nb2) { rbe2[nb2] = 0; rbs2[nb2] = 0; rbc2[nb2] = 0; }
    }
}

// ---------------- scatter rows into expert-grouped perm ----------------------
__global__ void scatter_kernel(const int* __restrict__ idx, const int* __restrict__ offs,
                               int* __restrict__ cur, int* __restrict__ perm) {
    int r = blockIdx.x * 256 + threadIdx.x;   // 8192 rows
    int e = idx[r];
    int p = atomicAdd(&cur[e], 1);
    perm[offs[e] + p] = r;
}

// ---------------- one-time casts ---------------------------------------------
__global__ void castx_kernel(const float* __restrict__ x, ushort* __restrict__ xb) {
    int t = blockIdx.x * 256 + threadIdx.x;
    float4 v = *(const float4*)(x + (size_t)t * 4);
    union { __bf16 h[4]; uint2 u; } pk;
    pk.h[0] = (__bf16)v.x; pk.h[1] = (__bf16)v.y;
    pk.h[2] = (__bf16)v.z; pk.h[3] = (__bf16)v.w;
    *(uint2*)(xb + (size_t)t * 4) = pk.u;
}

// grid (12,16,4): e, 64-d tile, 64-ed tile.  wmapT[e][ed][d] = bf16(w_map[e][d][ed])
__global__ void castw_kernel(const float* __restrict__ wmap, ushort* __restrict__ wmapT) {
    int e = blockIdx.x, dt = blockIdx.y, et = blockIdx.z;
    __shared__ float ls[64][65];
    int c = threadIdx.x & 63, rg = threadIdx.x >> 6;
    const float* src = wmap + (size_t)e * (D_ * ED_) + (size_t)(dt * 64) * ED_ + et * 64;
#pragma unroll
    for (int q = 0; q < 16; ++q) {
        int r = q * 4 + rg;
        ls[r][c] = src[(size_t)r * ED_ + c];
    }
    __syncthreads();
    ushort* dst = wmapT + ((size_t)e << 18) + (size_t)(et * 64) * 1024 + dt * 64;
#pragma unroll
    for (int q = 0; q < 16; ++q) {
        int r = q * 4 + rg;
        union { __bf16 h; ushort u; } cv; cv.h = (__bf16)ls[c][r];
        dst[(size_t)r * 1024 + c] = cv.u;
    }
}

// grid (2,16,4): which, 64-d tile, 64-ed tile. wT[ed][d] = bf16(w[d][ed])
__global__ void castwkv_kernel(const float* __restrict__ wk, const float* __restrict__ wv,
                               ushort* __restrict__ wkT, ushort* __restrict__ wvT) {
    int which = blockIdx.x, dt = blockIdx.y, et = blockIdx.z;
    const float* w = which ? wv : wk;
    ushort* wT = which ? wvT : wkT;
    __shared__ float ls[64][65];
    int c = threadIdx.x & 63, rg = threadIdx.x >> 6;
    const float* src = w + (size_t)(dt * 64) * ED_ + et * 64;
#pragma unroll
    for (int q = 0; q < 16; ++q) {
        int r = q * 4 + rg;
        ls[r][c] = src[(size_t)r * ED_ + c];
    }
    __syncthreads();
    ushort* dst = wT + (size_t)(et * 64) * 1024 + dt * 64;
#pragma unroll
    for (int q = 0; q < 16; ++q) {
        int r = q * 4 + rg;
        union { __bf16 h; ushort u; } cv; cv.h = (__bf16)ls[c][r];
        dst[(size_t)r * 1024 + c] = cv.u;
    }
}

// grid (12,4,16): e, 64-ed tile, 64-d tile.
// wredT3[e][d][k]: k in [0,256)=w_hi[ed], [256,512)=w_hi[ed], [512,768)=w_lo[ed]
__global__ void castwred_kernel(const float* __restrict__ wred, ushort* __restrict__ wredT3) {
    int e = blockIdx.x, et = blockIdx.y, dt = blockIdx.z;
    __shared__ float ls[64][65];
    int c = threadIdx.x & 63, rg = threadIdx.x >> 6;
    const float* src = wred + (size_t)e * (ED_ * D_) + (size_t)(et * 64) * D_ + dt * 64;
#pragma unroll
    for (int q = 0; q < 16; ++q) {
        int r = q * 4 + rg;           // ed-local
        ls[r][c] = src[(size_t)r * D_ + c];
    }
    __syncthreads();
    ushort* dst = wredT3 + (size_t)e * (D_ * KR_) + (size_t)(dt * 64) * KR_ + et * 64;
#pragma unroll
    for (int q = 0; q < 16; ++q) {
        int r = q * 4 + rg;           // d-local
        float v = ls[c][r];
        union { __bf16 h; ushort u; } hi; hi.h = (__bf16)v;
        float lo = v - (float)hi.h;
        union { __bf16 h; ushort u; } lov; lov.h = (__bf16)lo;
        dst[(size_t)r * KR_ + c] = hi.u;
        dst[(size_t)r * KR_ + 256 + c] = hi.u;
        dst[(size_t)r * KR_ + 512 + c] = lov.u;
    }
}

// ---------------- k/v projection as bf16 MFMA GEMM ---------------------------
__global__ void __launch_bounds__(256)
kv_mfma(const ushort* __restrict__ keyb, const ushort* __restrict__ valb,
        const ushort* __restrict__ wkT, const ushort* __restrict__ wvT,
        ushort* __restrict__ kpb, ushort* __restrict__ vpT) {
    int which = blockIdx.y;
    const ushort* xb = which ? valb : keyb;
    const ushort* wT = which ? wvT : wkT;
    int m0 = blockIdx.x * 32;
    int b = m0 >> 10, t0 = m0 & 1023;
    int tid = threadIdx.x, w = tid >> 6, L = tid & 63;
    __shared__ __align__(16) ushort As[2][32 * 64];
    __shared__ __align__(16) ushort Bs[2][4 * 64 * 64];

    int swz = ((L & 7) ^ ((L >> 3) & 7)) * 8;
    int an = (((t0 + w * 8 + (L >> 3)) << 1) | b);
    const ushort* asrc = xb + (size_t)an * 1024 + swz;
    const ushort* bsrc = wT + (size_t)(w * 64 + (L >> 3)) * 1024 + swz;

    f32x4 acc[2][4];
#pragma unroll
    for (int mt = 0; mt < 2; ++mt)
#pragma unroll
        for (int nt = 0; nt < 4; ++nt) acc[mt][nt] = (f32x4){0.f, 0.f, 0.f, 0.f};

    auto stage = [&](int kt, int bf) {
        async16(asrc + kt * 64, &As[bf][w * 512]);
#pragma unroll
        for (int q = 0; q < 8; ++q)
            async16(bsrc + (size_t)q * 8192 + kt * 64, &Bs[bf][(w * 64 + q * 8) * 64]);
    };
    auto compute = [&](int bf) {
        const ushort* AB = As[bf];
        const ushort* BB = Bs[bf] + w * 4096;
#pragma unroll
        for (int ks = 0; ks < 2; ++ks) {
            int phys = (((ks * 4 + (L >> 4)) ^ (L & 7))) * 8;
            bf16x8 a0 = *(const bf16x8*)(AB + (L & 15) * 64 + phys);
            bf16x8 a1 = *(const bf16x8*)(AB + (16 + (L & 15)) * 64 + phys);
#pragma unroll
            for (int nt = 0; nt < 4; ++nt) {
                bf16x8 bfr = *(const bf16x8*)(BB + (nt * 16 + (L & 15)) * 64 + phys);
                acc[0][nt] = __builtin_amdgcn_mfma_f32_16x16x32_bf16(a0, bfr, acc[0][nt], 0, 0, 0);
                acc[1][nt] = __builtin_amdgcn_mfma_f32_16x16x32_bf16(a1, bfr, acc[1][nt], 0, 0, 0);
            }
        }
    };

    stage(0, 0);
    for (int t = 0; t < 16; ++t) {
        __syncthreads();
        if (t < 15) stage(t + 1, (t + 1) & 1);
        compute(t & 1);
    }

#pragma unroll
    for (int mt = 0; mt < 2; ++mt)
#pragma unroll
        for (int nt = 0; nt < 4; ++nt) {
            int ed = w * 64 + nt * 16 + (L & 15);
            int tb = t0 + mt * 16 + (L >> 4) * 4;
            if (which == 0) {
#pragma unroll
                for (int r = 0; r < 4; ++r) {
                    union { __bf16 h; ushort u; } cv;
                    cv.h = (__bf16)(acc[mt][nt][r] * sc_());
                    kpb[((size_t)((b << 10) + tb + r)) * ED_ + ed] = cv.u;
                }
            } else {
                int h = ed >> 6, d = ed & 63;
                union { __bf16 h4[4]; uint2 u; } pk;
#pragma unroll
                for (int r = 0; r < 4; ++r) pk.h4[r] = (__bf16)acc[mt][nt][r];
                *(uint2*)&vpT[((size_t)((b * 4 + h) * 64 + d)) * 1024 + tb] = pk.u;
            }
        }
}

// ---------------- q projection as bf16 MFMA GEMM per 32-row expert chunk -----
__global__ void __launch_bounds__(256)
qproj_mfma(const ushort* __restrict__ xb, const ushort* __restrict__ wmapT,
           const int* __restrict__ perm,
           const int* __restrict__ rbe2, const int* __restrict__ rbs2,
           const int* __restrict__ rbc2,
           float* __restrict__ qp, ushort* __restrict__ qpb) {
    int blk = blockIdx.x;
    int nr = rbc2[blk];
    if (nr == 0) return;
    int e = rbe2[blk], rs = rbs2[blk];
    int tid = threadIdx.x, w = tid >> 6, L = tid & 63;
    __shared__ __align__(16) ushort As[2][32 * 64];
    __shared__ __align__(16) ushort Bs[2][4 * 64 * 64];
    __shared__ int rows2[32];
    if (tid < 32) rows2[tid] = (tid < nr) ? perm[rs + tid] : -1;
    __syncthreads();

    int swz = ((L & 7) ^ ((L >> 3) & 7)) * 8;
    int ar = rows2[w * 8 + (L >> 3)];
    const ushort* asrc = xb + (size_t)((ar < 0 ? 0 : ar) >> 2) * 1024 + swz;
    const ushort* bsrc = wmapT + ((size_t)e << 18) + (size_t)(w * 64 + (L >> 3)) * 1024 + swz;

    f32x4 acc[2][4];
#pragma unroll
    for (int mt = 0; mt < 2; ++mt)
#pragma unroll
        for (int nt = 0; nt < 4; ++nt) acc[mt][nt] = (f32x4){0.f, 0.f, 0.f, 0.f};

    auto stage = [&](int kt, int bf) {
        async16(asrc + kt * 64, &As[bf][w * 512]);
#pragma unroll
        for (int q = 0; q < 8; ++q)
            async16(bsrc + (size_t)q * 8192 + kt * 64, &Bs[bf][(w * 64 + q * 8) * 64]);
    };
    auto compute = [&](int bf) {
        const ushort* AB = As[bf];
        const ushort* BB = Bs[bf] + w * 4096;
#pragma unroll
        for (int ks = 0; ks < 2; ++ks) {
            int phys = (((ks * 4 + (L >> 4)) ^ (L & 7))) * 8;
            bf16x8 a0 = *(const bf16x8*)(AB + (L & 15) * 64 + phys);
            bf16x8 a1 = *(const bf16x8*)(AB + (16 + (L & 15)) * 64 + phys);
#pragma unroll
            for (int nt = 0; nt < 4; ++nt) {
                bf16x8 b = *(const bf16x8*)(BB + (nt * 16 + (L & 15)) * 64 + phys);
                acc[0][nt] = __builtin_amdgcn_mfma_f32_16x16x32_bf16(a0, b, acc[0][nt], 0, 0, 0);
                acc[1][nt] = __builtin_amdgcn_mfma_f32_16x16x32_bf16(a1, b, acc[1][nt], 0, 0, 0);
            }
        }
    };

    stage(0, 0);
    for (int t = 0; t < 16; ++t) {
        __syncthreads();
        if (t < 15) stage(t + 1, (t + 1) & 1);
        compute(t & 1);
    }

#pragma unroll
    for (int mt = 0; mt < 2; ++mt)
#pragma unroll
        for (int nt = 0; nt < 4; ++nt) {
            int n = w * 64 + nt * 16 + (L & 15);
#pragma unroll
            for (int r = 0; r < 4; ++r) {
                int m = mt * 16 + (L >> 4) * 4 + r;
                int rowg = rows2[m];
                if (rowg >= 0) {
                    float v = acc[mt][nt][r] * sc_();
                    qp[(size_t)rowg * ED_ + n] = v;
                    union { __bf16 h; ushort u; } cv; cv.h = (__bf16)v;
                    qpb[(size_t)rowg * ED_ + n] = cv.u;
                }
            }
        }
}

// ---------------- rel bias table: rel[bkh,i,p] = q_row . rpe[h,:,p] ----------
__global__ void rel_kernel(const float* __restrict__ qp, const float* __restrict__ rpe,
                           float* __restrict__ rel) {
    int Rr = blockIdx.x * 2 + (threadIdx.x >> 7);
    int p = threadIdx.x & 127;
    int i = Rr & 1023, h = (Rr >> 10) & 3, kk = (Rr >> 12) & 3, bb = Rr >> 14;
    int row = ((i * 2 + bb) << 2) | kk;
    int qbase = __builtin_amdgcn_readfirstlane(row * ED_ + h * HD_);
    int hbase = __builtin_amdgcn_readfirstlane(h * HD_);
    float acc = 0.f;
    for (int d = 0; d < HD_; ++d)
        acc += qp[qbase + d] * rpe[(hbase + d) * 129 + p];
    rel[Rr * 128 + p] = acc;
}

// ---------------- MFMA flash attention (bf16, no-max softmax) ----------------
// epilogue writes split-precision azd[row][768] = [a_hi | a_lo | a_hi] (bf16)
__global__ void __launch_bounds__(256)
attn_kernel(const ushort* __restrict__ qpb, const ushort* __restrict__ kpb,
            const ushort* __restrict__ vpT, const float* __restrict__ rel,
            const float* __restrict__ gates, ushort* __restrict__ azd) {
    __shared__ __align__(16) ushort Ks[2][64 * 64];
    __shared__ __align__(16) ushort Vs[2][64 * 64];
    __shared__ __align__(16) ushort Ps[4][16 * 64];

    const int tid = threadIdx.x;
    const int w = tid >> 6, L = tid & 63;
    const int bkh = blockIdx.x & 31, it = blockIdx.x >> 5;
    const int h = bkh & 3, kk = (bkh >> 2) & 3, bb = bkh >> 4;
    const int i0w = it * 64 + w * 16;
    const int iL = i0w + (L & 15);
    const int row = ((iL * 2 + bb) << 2) | kk;

    const ushort* qrow = qpb + row * ED_ + h * HD_;
    bf16x8 qf0 = *(const bf16x8*)(qrow + (L >> 4) * 8);
    bf16x8 qf1 = *(const bf16x8*)(qrow + 32 + (L >> 4) * 8);

    const float* relrow = rel + ((size_t)((bkh << 10) + iL)) * 128;
    float rel_lo = relrow[1], rel_hi = relrow[127];
    float gate = gates[row];

    f32x4 O[4];
#pragma unroll
    for (int mf = 0; mf < 4; ++mf) O[mf] = (f32x4){0.f, 0.f, 0.f, 0.f};
    float l_acc = 0.f;

    const ushort* ksrc = kpb + (size_t)(bb << 10) * ED_ + h * HD_;
    const ushort* vsrc = vpT + (size_t)((bb * 4 + h) * 64) * 1024;

    auto stage = [&](int t, int bf) {
        int j0 = t * 64;
#pragma unroll
        for (int q = 0; q < 2; ++q) {
            int r = L >> 3;
            int c = (L & 7) ^ r;
            const ushort* src = ksrc + (size_t)(j0 + w * 16 + q * 8 + r) * ED_ + c * 8;
            async16(src, &Ks[bf][(w * 16 + q * 8) * 64]);
        }
#pragma unroll
        for (int q = 0; q < 2; ++q) {
            int r = L >> 3;
            int d = w * 16 + q * 8 + r;
            int c = (L & 7) ^ (d & 7);
            const ushort* src = vsrc + (size_t)d * 1024 + j0 + c * 8;
            async16(src, &Vs[bf][(w * 16 + q * 8) * 64]);
        }
    };

    auto compute = [&](int bf, int j0) {
        const ushort* KB = Ks[bf];
        const ushort* VB = Vs[bf];
        ushort* PW = Ps[w];
#pragma unroll
        for (int jf = 0; jf < 4; ++jf) {
            int jrow = jf * 16 + (L & 15);
            bf16x8 a0 = *(const bf16x8*)(KB + jrow * 64 + (((L >> 4)) ^ (L & 7)) * 8);
            bf16x8 a1 = *(const bf16x8*)(KB + jrow * 64 + ((4 + (L >> 4)) ^ (L & 7)) * 8);
            f32x4 s = (f32x4){0.f, 0.f, 0.f, 0.f};
            s = __builtin_amdgcn_mfma_f32_16x16x32_bf16(a0, qf0, s, 0, 0, 0);
            s = __builtin_amdgcn_mfma_f32_16x16x32_bf16(a1, qf1, s, 0, 0, 0);
            int jlo = j0 + jf * 16;
            int jbase = jlo + (L >> 4) * 4;
            float pv[4];
            if (jlo >= i0w + 78) {
#pragma unroll
                for (int r = 0; r < 4; ++r) pv[r] = __expf(s[r] + rel_hi);
            } else if (jlo <= i0w - 78) {
#pragma unroll
                for (int r = 0; r < 4; ++r) pv[r] = __expf(s[r] + rel_lo);
            } else {
#pragma unroll
                for (int r = 0; r < 4; ++r) {
                    int dj = jbase + r - iL;
                    dj = dj < -63 ? -63 : (dj > 63 ? 63 : dj);
                    pv[r] = __expf(s[r] + relrow[dj + 64]);
                }
            }
            l_acc += (pv[0] + pv[1]) + (pv[2] + pv[3]);
            union { __bf16 h4[4]; uint2 u; } pk;
#pragma unroll
            for (int r = 0; r < 4; ++r) pk.h4[r] = (__bf16)pv[r];
            int iloc = L & 15;
            int chunk = jf * 2 + ((L >> 4) >> 1);
            int phys = chunk ^ (iloc & 7);
            *(uint2*)(PW + iloc * 64 + phys * 8 + ((L >> 4) & 1) * 4) = pk.u;
        }
#pragma unroll
        for (int ks = 0; ks < 2; ++ks) {
            int c = ks * 4 + (L >> 4);
            int phys = c ^ (L & 7);
            bf16x8 pf = *(const bf16x8*)(PW + (L & 15) * 64 + phys * 8);
#pragma unroll
            for (int mf = 0; mf < 4; ++mf) {
                bf16x8 vf = *(const bf16x8*)(VB + (mf * 16 + (L & 15)) * 64 + phys * 8);
                O[mf] = __builtin_amdgcn_mfma_f32_16x16x32_bf16(vf, pf, O[mf], 0, 0, 0);
            }
        }
    };

    stage(0, 0);
    for (int t = 0; t < 16; ++t) {
        __syncthreads();
        if (t < 15) stage(t + 1, (t + 1) & 1);
        compute(t & 1, t * 64);
    }

    l_acc += __shfl_xor(l_acc, 16);
    l_acc += __shfl_xor(l_acc, 32);
    float inv = gate / l_acc;
    ushort* azrow = azd + (size_t)row * KR_ + h * HD_;
#pragma unroll
    for (int mf = 0; mf < 4; ++mf) {
        union { __bf16 h4[4]; uint2 u; } hi, lo;
#pragma unroll
        for (int r = 0; r < 4; ++r) {
            float v = O[mf][r] * inv;
            hi.h4[r] = (__bf16)v;
            lo.h4[r] = (__bf16)(v - (float)hi.h4[r]);
        }
        int off = mf * 16 + (L >> 4) * 4;
        *(uint2*)(azrow + off) = hi.u;
        *(uint2*)(azrow + 256 + off) = lo.u;
        *(uint2*)(azrow + 512 + off) = hi.u;
    }
}

// ---------------- expert reduce as bf16 MFMA (split precision, K=768) --------
// grid (PB_MAX, 4): 32-row chunk, d-quarter. z4[row][1024] = azd[row] @ wredT3[e]
__global__ void __launch_bounds__(256)
reduce_mfma(const ushort* __restrict__ azd, const ushort* __restrict__ wredT3,
            const int* __restrict__ perm,
            const int* __restrict__ rbe2, const int* __restrict__ rbs2,
            const int* __restrict__ rbc2, float* __restrict__ z4) {
    int blk = blockIdx.x;
    int nr = rbc2[blk];
    if (nr == 0) return;
    int e = rbe2[blk], rs = rbs2[blk];
    int n0 = blockIdx.y * 256;
    int tid = threadIdx.x, w = tid >> 6, L = tid & 63;
    __shared__ __align__(16) ushort As[2][32 * 64];
    __shared__ __align__(16) ushort Bs[2][4 * 64 * 64];
    __shared__ int rows2[32];
    if (tid < 32) rows2[tid] = (tid < nr) ? perm[rs + tid] : -1;
    __syncthreads();

    int swz = ((L & 7) ^ ((L >> 3) & 7)) * 8;
    int ar = rows2[w * 8 + (L >> 3)];
    const ushort* asrc = azd + (size_t)(ar < 0 ? 0 : ar) * KR_ + swz;
    const ushort* bsrc = wredT3 + (size_t)e * (D_ * KR_)
                       + (size_t)(n0 + w * 64 + (L >> 3)) * KR_ + swz;

    f32x4 acc[2][4];
#pragma unroll
    for (int mt = 0; mt < 2; ++mt)
#pragma unroll
        for (int nt = 0; nt < 4; ++nt) acc[mt][nt] = (f32x4){0.f, 0.f, 0.f, 0.f};

    auto stage = [&](int kt, int bf) {
        async16(asrc + kt * 64, &As[bf][w * 512]);
#pragma unroll
        for (int q = 0; q < 8; ++q)
            async16(bsrc + (size_t)q * (8 * KR_) + kt * 64, &Bs[bf][(w * 64 + q * 8) * 64]);
    };
    auto compute = [&](int bf) {
        const ushort* AB = As[bf];
        const ushort* BB = Bs[bf] + w * 4096;
#pragma unroll
        for (int ks = 0; ks < 2; ++ks) {
            int phys = (((ks * 4 + (L >> 4)) ^ (L & 7))) * 8;
            bf16x8 a0 = *(const bf16x8*)(AB + (L & 15) * 64 + phys);
            bf16x8 a1 = *(const bf16x8*)(AB + (16 + (L & 15)) * 64 + phys);
#pragma unroll
            for (int nt = 0; nt < 4; ++nt) {
                bf16x8 b = *(const bf16x8*)(BB + (nt * 16 + (L & 15)) * 64 + phys);
                acc[0][nt] = __builtin_amdgcn_mfma_f32_16x16x32_bf16(a0, b, acc[0][nt], 0, 0, 0);
                acc[1][nt] = __builtin_amdgcn_mfma_f32_16x16x32_bf16(a1, b, acc[1][nt], 0, 0, 0);
            }
        }
    };

    stage(0, 0);
    for (int t = 0; t < 12; ++t) {       // K = 768 -> 12 tiles of 64
        __syncthreads();
        if (t < 11) stage(t + 1, (t + 1) & 1);
        compute(t & 1);
    }

#pragma unroll
    for (int mt = 0; mt < 2; ++mt)
#pragma unroll
        for (int nt = 0; nt < 4; ++nt) {
            int n = n0 + w * 64 + nt * 16 + (L & 15);
#pragma unroll
            for (int r = 0; r < 4; ++r) {
                int m = mt * 16 + (L >> 4) * 4 + r;
                int rowg = rows2[m];
                if (rowg >= 0) z4[(size_t)rowg * D_ + n] = acc[mt][nt][r];
            }
        }
}

// ---------------- combine: out[n] = sum_k z4[n*4+k] --------------------------
__global__ void combine_out(const float* __restrict__ z4, float* __restrict__ out) {
    int t = blockIdx.x * 256 + threadIdx.x;     // N_*D_/4 threads
    int n = t >> 8, d0 = (t & 255) * 4;
    const float* zr = z4 + (size_t)(n * 4) * D_ + d0;
    float4 a = *(const float4*)(zr);
    float4 b = *(const float4*)(zr + D_);
    float4 c = *(const float4*)(zr + 2 * D_);
    float4 d = *(const float4*)(zr + 3 * D_);
    float4 s = make_float4(a.x + b.x + c.x + d.x, a.y + b.y + c.y + d.y,
                           a.z + b.z + c.z + d.z, a.w + b.w + c.w + d.w);
    *(float4*)(out + (size_t)n * D_ + d0) = s;
}

// ---------------- launcher ---------------------------------------------------
extern "C" void kernel_launch(void* const* d_in, const int* in_sizes, int n_in,
                              void* d_out, int out_size, void* d_ws, size_t ws_size,
                              hipStream_t stream) {
    const float* query = (const float*)d_in[0];
    const float* key   = (const float*)d_in[1];
    const float* value = (const float*)d_in[2];
    const float* wg    = (const float*)d_in[3];
    const float* wmap  = (const float*)d_in[4];
    const float* wred  = (const float*)d_in[5];
    const float* wk    = (const float*)d_in[6];
    const float* wv    = (const float*)d_in[7];
    const float* rpe   = (const float*)d_in[8];
    float* out = (float*)d_out;

    char* ws = (char*)d_ws;
    float*  gates = (float*)(ws + 0);                      // 32 KB
    int*    idx   = (int*)(ws + (32 << 10));               // 32 KB
    char*   misc  = ws + (64 << 10);
    int*    counts = (int*)(misc + 0);                     // [zeroed]
    int*    cur    = (int*)(misc + 64);                    // [zeroed]
    int*    offs   = (int*)(misc + 128);
    int*    rbe2   = (int*)(misc + 8192);
    int*    rbs2   = (int*)(misc + 9472);
    int*    rbc2   = (int*)(misc + 10752);
    int*    perm  = (int*)(ws + (96 << 10));               // 32 KB
    char*   base  = ws + (128 << 10);
    float*  qp    = (float*)(base);                        // 8 MB f32 (rel input)
    ushort* qpb   = (ushort*)(base + (8u  << 20));         // 4 MB
    ushort* kpb   = (ushort*)(base + (12u << 20));         // 1 MB [b][t][ed]
    ushort* vpT   = (ushort*)(base + (13u << 20));         // 1 MB [b][h][d][t]
    ushort* xb    = (ushort*)(base + (14u << 20));         // 4 MB  (dead before reduce)
    ushort* wmapT = (ushort*)(base + (18u << 20));         // 6 MB  (dead before reduce)
    ushort* keyb  = (ushort*)(base + (24u << 20));         // 4 MB  (dead before reduce)
    ushort* valb  = (ushort*)(base + (28u << 20));         // 4 MB  (dead before reduce)
    ushort* wkT   = (ushort*)(base + (32u << 20));         // 0.5 MB
    ushort* wvT   = (ushort*)(base + (32u << 20) + (512u << 10)); // 0.5 MB
    float*  z4    = (float*)(base + (14u << 20));          // 33.5 MB, overlaps xb..wvT (dead)
    ushort* azd   = (ushort*)(base + (48u << 20));         // 12.6 MB [row][768]
    ushort* wredT3= (ushort*)(base + (61u << 20));         // 18.9 MB [e][d][768]
    float*  rel   = (float*)(base + (80u << 20));          // 16 MB

    hipMemsetAsync(misc, 0, 128, stream);

    castx_kernel<<<(N_ * D_) / 1024, 256, 0, stream>>>(query, xb);
    castx_kernel<<<(N_ * D_) / 1024, 256, 0, stream>>>(key, keyb);
    castx_kernel<<<(N_ * D_) / 1024, 256, 0, stream>>>(value, valb);
    castw_kernel<<<dim3(E_, 16, 4), 256, 0, stream>>>(wmap, wmapT);
    castwkv_kernel<<<dim3(2, 16, 4), 256, 0, stream>>>(wk, wv, wkT, wvT);
    castwred_kernel<<<dim3(E_, 4, 16), 256, 0, stream>>>(wred, wredT3);
    gate_kernel<<<N_, 64, 0, stream>>>(query, wg, gates, idx, counts);
    scan_kernel<<<1, 64, 0, stream>>>(counts, offs, rbe2, rbs2, rbc2);
    scatter_kernel<<<NROW / 256, 256, 0, stream>>>(idx, offs, cur, perm);
    kv_mfma<<<dim3(64, 2), 256, 0, stream>>>(keyb, valb, wkT, wvT, kpb, vpT);
    qproj_mfma<<<PB_MAX, 256, 0, stream>>>(xb, wmapT, perm, rbe2, rbs2, rbc2, qp, qpb);
    rel_kernel<<<(32 * T_) / 2, 256, 0, stream>>>(qp, rpe, rel);
    attn_kernel<<<512, 256, 0, stream>>>(qpb, kpb, vpT, rel, gates, azd);
    reduce_mfma<<<dim3(PB_MAX, 4), 256, 0, stream>>>(azd, wredT3, perm, rbe2, rbs2, rbc2, z4);
    combine_out<<<(N_ * D_) / 1024, 256, 0, stream>>>(z4, out);
}